// Round 3
// baseline (1144.244 us; speedup 1.0000x reference)
//
#include <hip/hip_runtime.h>

#define LSZ   16
#define NBATCH 2
#define NSITE (NBATCH*LSZ*LSZ*LSZ*LSZ)   // 131072
#define NIN   10
#define NOUT  8
#define ND    4
#define NCPLX ((long)NSITE * NOUT * 9)   // 9,437,184 complex output elements

typedef unsigned int u32;

struct M3 { float re[9]; float im[9]; };

// ---- W storage: fp32 (float2) or packed bf16 (u32: low=re, high=im) ----
__device__ __forceinline__ unsigned short f2bf(float x) {
    u32 u = __float_as_uint(x);
    u32 r = (u + 0x7fffu + ((u >> 16) & 1u)) >> 16;   // RNE
    return (unsigned short)r;
}
__device__ __forceinline__ void w_store(float2* W, long idx, float re, float im) {
    W[idx] = make_float2(re, im);
}
__device__ __forceinline__ void w_store(u32* W, long idx, float re, float im) {
    W[idx] = (u32)f2bf(re) | ((u32)f2bf(im) << 16);
}
__device__ __forceinline__ float2 w_load(const float2* W, long idx) { return W[idx]; }
__device__ __forceinline__ float2 w_load(const u32* W, long idx) {
    u32 v = W[idx];
    return make_float2(__uint_as_float(v << 16), __uint_as_float(v & 0xffff0000u));
}

__device__ __forceinline__ void loadM(M3& m, const float* __restrict__ Ure,
                                      const float* __restrict__ Uim, long off) {
#pragma unroll
    for (int e = 0; e < 9; e++) { m.re[e] = Ure[off + e]; m.im[e] = Uim[off + e]; }
}

// o = a * b
__device__ __forceinline__ void mulM(M3& o, const M3& a, const M3& b) {
#pragma unroll
    for (int r = 0; r < 3; r++) {
#pragma unroll
        for (int c = 0; c < 3; c++) {
            float xr = 0.f, xi = 0.f;
#pragma unroll
            for (int k = 0; k < 3; k++) {
                float ar = a.re[r*3+k], ai = a.im[r*3+k];
                float br = b.re[k*3+c], bi = b.im[k*3+c];
                xr = fmaf(ar, br, xr); xr = fmaf(-ai, bi, xr);
                xi = fmaf(ar, bi, xi); xi = fmaf(ai, br, xi);
            }
            o.re[r*3+c] = xr; o.im[r*3+c] = xi;
        }
    }
}

// o = a * b^H
__device__ __forceinline__ void mulAdjM(M3& o, const M3& a, const M3& b) {
#pragma unroll
    for (int r = 0; r < 3; r++) {
#pragma unroll
        for (int c = 0; c < 3; c++) {
            float xr = 0.f, xi = 0.f;
#pragma unroll
            for (int k = 0; k < 3; k++) {
                float ar = a.re[r*3+k], ai = a.im[r*3+k];
                float br = b.re[c*3+k], bi = b.im[c*3+k];
                xr = fmaf(ar, br, xr); xr = fmaf(ai, bi, xr);
                xi = fmaf(ai, br, xi); xi = fmaf(-ar, bi, xi);
            }
            o.re[r*3+c] = xr; o.im[r*3+c] = xi;
        }
    }
}

// site s = b*65536 + x*4096 + y*256 + z*16 + t ; mu: 0->x,1->y,2->z,3->t
__device__ __forceinline__ int shift_site(int s, int mu, int k) {
    int sh = 12 - 4 * mu;
    int c  = (s >> sh) & 15;
    int nc = (c + k) & 15;
    return (s & ~(15 << sh)) | (nc << sh);
}

// ---------------- Kernel 1: plaquettes -> W channels 0..5 ----------------
template <typename WT>
__global__ __launch_bounds__(256) void plaq_kernel(const float* __restrict__ Ure,
                                                   const float* __restrict__ Uim,
                                                   WT* __restrict__ W) {
    int tid = blockIdx.x * blockDim.x + threadIdx.x;
    int p = tid / NSITE;            // 0..5, wave-uniform
    int s = tid - p * NSITE;
    int mu = (p < 3) ? 0 : ((p < 5) ? 1 : 2);
    int nu = (mu == 0) ? (p + 1) : ((mu == 1) ? (p - 1) : 3);

    M3 Umu, Unu, Unu_f, Umu_f, T1, T2, P;
    loadM(Umu, Ure, Uim, (long)(s * 4 + mu) * 9);
    loadM(Unu, Ure, Uim, (long)(s * 4 + nu) * 9);
    int spmu = shift_site(s, mu, 1);
    int spnu = shift_site(s, nu, 1);
    loadM(Unu_f, Ure, Uim, (long)(spmu * 4 + nu) * 9);   // U_nu(x+mu)
    loadM(Umu_f, Ure, Uim, (long)(spnu * 4 + mu) * 9);   // U_mu(x+nu)

    mulM(T1, Umu, Unu_f);
    mulAdjM(T2, T1, Umu_f);
    mulAdjM(P, T2, Unu);

    long base = ((long)s * NIN + p) * 9;
#pragma unroll
    for (int e = 0; e < 9; e++) w_store(W, base + e, P.re[e], P.im[e]);
}

// ---------------- Kernel 2: Polyakov loops -> W channels 6..9 ----------------
template <typename WT>
__global__ __launch_bounds__(256) void poly_kernel(const float* __restrict__ Ure,
                                                   const float* __restrict__ Uim,
                                                   WT* __restrict__ W) {
    int tid = blockIdx.x * blockDim.x + threadIdx.x;
    int mu = tid / NSITE;           // 0..3, wave-uniform
    int s  = tid - mu * NSITE;

    M3 P;
    loadM(P, Ure, Uim, (long)(s * 4 + mu) * 9);
    for (int step = 1; step < LSZ; step++) {
        int nb = shift_site(s, mu, step);
        M3 Un, T;
        loadM(Un, Ure, Uim, (long)(nb * 4 + mu) * 9);
        mulM(T, P, Un);
        P = T;
    }
    long base = ((long)s * NIN + 6 + mu) * 9;
#pragma unroll
    for (int e = 0; e < 9; e++) w_store(W, base + e, P.re[e], P.im[e]);
}

// ---------------- Kernel 3: gauge-equivariant conv ----------------
// mode 0: interleaved (re,im) pairs           (out_size == 2*NCPLX, complex view)
// mode 1: planar  [re block][im block]        (out_size == 2*NCPLX, stacked)
// mode 2: real part only                      (out_size == NCPLX)
template <typename WT>
__global__ __launch_bounds__(256) void conv_kernel(const float* __restrict__ Ure,
                                                   const float* __restrict__ Uim,
                                                   const float* __restrict__ omre,
                                                   const float* __restrict__ omim,
                                                   const WT* __restrict__ W,
                                                   float* __restrict__ out,
                                                   long out_limit, int mode) {
    __shared__ float2 som[NOUT * NIN * ND * 3];   // 960 * 8B = 7.5 KB
    for (int idx = threadIdx.x; idx < NOUT * NIN * ND * 3; idx += blockDim.x)
        som[idx] = make_float2(omre[idx], omim[idx]);
    __syncthreads();

    int tid = blockIdx.x * blockDim.x + threadIdx.x;
    int i = tid & 7;          // output channel
    int s = tid >> 3;         // site

    float accr[9] = {0,0,0,0,0,0,0,0,0};
    float acci[9] = {0,0,0,0,0,0,0,0,0};

    for (int mu = 0; mu < ND; mu++) {
        M3 Msum;
#pragma unroll
        for (int e = 0; e < 9; e++) { Msum.re[e] = 0.f; Msum.im[e] = 0.f; }

        for (int kk = 0; kk < 3; kk++) {            // k = kk-1
            int nb = shift_site(s, mu, kk - 1);
            long wbase = (long)nb * (NIN * 9);
            for (int j = 0; j < NIN; j++) {
                float2 om = som[((i * NIN + j) * ND + mu) * 3 + kk];
#pragma unroll
                for (int e = 0; e < 9; e++) {
                    float2 w = w_load(W, wbase + j * 9 + e);
                    Msum.re[e] = fmaf(om.x, w.x, Msum.re[e]);
                    Msum.re[e] = fmaf(-om.y, w.y, Msum.re[e]);
                    Msum.im[e] = fmaf(om.x, w.y, Msum.im[e]);
                    Msum.im[e] = fmaf(om.y, w.x, Msum.im[e]);
                }
            }
        }

        M3 A, T, R;
        loadM(A, Ure, Uim, (long)(s * 4 + mu) * 9);
        mulM(T, A, Msum);
        mulAdjM(R, T, A);
#pragma unroll
        for (int e = 0; e < 9; e++) { accr[e] += R.re[e]; acci[e] += R.im[e]; }
    }

    long cbase = (long)tid * 9;   // complex-element index of this thread's 3x3 block
    if (mode == 0) {
        long base = cbase * 2;
        if (base + 18 <= out_limit) {
            float2* op = (float2*)(out + base);
#pragma unroll
            for (int e = 0; e < 9; e++) op[e] = make_float2(accr[e], acci[e]);
        }
    } else if (mode == 1) {
        if (cbase + 9 <= NCPLX && NCPLX + cbase + 9 <= out_limit) {
#pragma unroll
            for (int e = 0; e < 9; e++) {
                out[cbase + e]         = accr[e];
                out[NCPLX + cbase + e] = acci[e];
            }
        }
    } else {
        if (cbase + 9 <= out_limit) {
#pragma unroll
            for (int e = 0; e < 9; e++) out[cbase + e] = accr[e];
        }
    }
}

extern "C" void kernel_launch(void* const* d_in, const int* in_sizes, int n_in,
                              void* d_out, int out_size, void* d_ws, size_t ws_size,
                              hipStream_t stream) {
    const float* Ure  = (const float*)d_in[0];
    const float* Uim  = (const float*)d_in[1];
    const float* omre = (const float*)d_in[2];
    const float* omim = (const float*)d_in[3];
    float* out = (float*)d_out;
    long out_limit = (long)out_size;

    // Disambiguate output layout from out_size:
    //   == NCPLX          -> harness stored real part only (complex->f32 cast)
    //   == 2*NCPLX        -> planar [re][im] (interleaved was disproved in R2:
    //                        writes happened, math verified, still absmax~ref)
    //   else              -> interleaved fallback
    int mode;
    if (out_size == (int)NCPLX)            mode = 2;
    else if (out_size == (int)(2 * NCPLX)) mode = 1;
    else                                   mode = 0;

    const size_t needA = (size_t)NSITE * NIN * 9 * sizeof(float2);  // 94.4 MB
    const size_t needB = (size_t)NSITE * NIN * 9 * sizeof(u32);     // 47.2 MB

    if (ws_size >= needA) {
        float2* W = (float2*)d_ws;
        plaq_kernel<float2><<<NSITE * 6 / 256, 256, 0, stream>>>(Ure, Uim, W);
        poly_kernel<float2><<<NSITE * 4 / 256, 256, 0, stream>>>(Ure, Uim, W);
        conv_kernel<float2><<<NSITE * 8 / 256, 256, 0, stream>>>(Ure, Uim, omre, omim, W, out, out_limit, mode);
    } else if (ws_size >= needB) {
        u32* W = (u32*)d_ws;
        plaq_kernel<u32><<<NSITE * 6 / 256, 256, 0, stream>>>(Ure, Uim, W);
        poly_kernel<u32><<<NSITE * 4 / 256, 256, 0, stream>>>(Ure, Uim, W);
        conv_kernel<u32><<<NSITE * 8 / 256, 256, 0, stream>>>(Ure, Uim, omre, omim, W, out, out_limit, mode);
    }
}

// Round 4
// 529.811 us; speedup vs baseline: 2.1597x; 2.1597x over previous
//
#include <hip/hip_runtime.h>

#define LSZ   16
#define NBATCH 2
#define NSITE (NBATCH*LSZ*LSZ*LSZ*LSZ)   // 131072
#define NIN   10
#define NOUT  8
#define ND    4
#define NCPLX ((long)NSITE * NOUT * 9)   // 9,437,184 complex output elements
#define NLINE_PER_DIR (NSITE / LSZ)      // 8192

typedef unsigned int u32;

struct M3 { float re[9]; float im[9]; };

// ---- W storage: fp32 (float2) or packed bf16 (u32: low=re, high=im) ----
__device__ __forceinline__ unsigned short f2bf(float x) {
    u32 u = __float_as_uint(x);
    u32 r = (u + 0x7fffu + ((u >> 16) & 1u)) >> 16;   // RNE
    return (unsigned short)r;
}
__device__ __forceinline__ void w_store(float2* W, long idx, float re, float im) {
    W[idx] = make_float2(re, im);
}
__device__ __forceinline__ void w_store(u32* W, long idx, float re, float im) {
    W[idx] = (u32)f2bf(re) | ((u32)f2bf(im) << 16);
}
__device__ __forceinline__ float2 w_load(const float2* W, long idx) { return W[idx]; }
__device__ __forceinline__ float2 w_load(const u32* W, long idx) {
    u32 v = W[idx];
    return make_float2(__uint_as_float(v << 16), __uint_as_float(v & 0xffff0000u));
}

__device__ __forceinline__ void loadM(M3& m, const float* __restrict__ Ure,
                                      const float* __restrict__ Uim, long off) {
#pragma unroll
    for (int e = 0; e < 9; e++) { m.re[e] = Ure[off + e]; m.im[e] = Uim[off + e]; }
}

// o = a * b
__device__ __forceinline__ void mulM(M3& o, const M3& a, const M3& b) {
#pragma unroll
    for (int r = 0; r < 3; r++) {
#pragma unroll
        for (int c = 0; c < 3; c++) {
            float xr = 0.f, xi = 0.f;
#pragma unroll
            for (int k = 0; k < 3; k++) {
                float ar = a.re[r*3+k], ai = a.im[r*3+k];
                float br = b.re[k*3+c], bi = b.im[k*3+c];
                xr = fmaf(ar, br, xr); xr = fmaf(-ai, bi, xr);
                xi = fmaf(ar, bi, xi); xi = fmaf(ai, br, xi);
            }
            o.re[r*3+c] = xr; o.im[r*3+c] = xi;
        }
    }
}

// o = a * b^H
__device__ __forceinline__ void mulAdjM(M3& o, const M3& a, const M3& b) {
#pragma unroll
    for (int r = 0; r < 3; r++) {
#pragma unroll
        for (int c = 0; c < 3; c++) {
            float xr = 0.f, xi = 0.f;
#pragma unroll
            for (int k = 0; k < 3; k++) {
                float ar = a.re[r*3+k], ai = a.im[r*3+k];
                float br = b.re[c*3+k], bi = b.im[c*3+k];
                xr = fmaf(ar, br, xr); xr = fmaf(ai, bi, xr);
                xi = fmaf(ai, br, xi); xi = fmaf(-ar, bi, xi);
            }
            o.re[r*3+c] = xr; o.im[r*3+c] = xi;
        }
    }
}

// site s = b*65536 + x*4096 + y*256 + z*16 + t ; mu: 0->x,1->y,2->z,3->t
__device__ __forceinline__ int shift_site(int s, int mu, int k) {
    int sh = 12 - 4 * mu;
    int c  = (s >> sh) & 15;
    int nc = (c + k) & 15;
    return (s & ~(15 << sh)) | (nc << sh);
}

// ---------------- Kernel 1: plaquettes -> W channels 0..5 ----------------
template <typename WT>
__global__ __launch_bounds__(256) void plaq_kernel(const float* __restrict__ Ure,
                                                   const float* __restrict__ Uim,
                                                   WT* __restrict__ W) {
    int tid = blockIdx.x * blockDim.x + threadIdx.x;
    int p = tid / NSITE;            // 0..5, wave-uniform
    int s = tid - p * NSITE;
    int mu = (p < 3) ? 0 : ((p < 5) ? 1 : 2);
    int nu = (mu == 0) ? (p + 1) : ((mu == 1) ? (p - 1) : 3);

    M3 Umu, Unu, Unu_f, Umu_f, T1, T2, P;
    loadM(Umu, Ure, Uim, (long)(s * 4 + mu) * 9);
    loadM(Unu, Ure, Uim, (long)(s * 4 + nu) * 9);
    int spmu = shift_site(s, mu, 1);
    int spnu = shift_site(s, nu, 1);
    loadM(Unu_f, Ure, Uim, (long)(spmu * 4 + nu) * 9);   // U_nu(x+mu)
    loadM(Umu_f, Ure, Uim, (long)(spnu * 4 + mu) * 9);   // U_mu(x+nu)

    mulM(T1, Umu, Unu_f);
    mulAdjM(T2, T1, Umu_f);
    mulAdjM(P, T2, Unu);

    long base = ((long)s * NIN + p) * 9;
#pragma unroll
    for (int e = 0; e < 9; e++) w_store(W, base + e, P.re[e], P.im[e]);
}

// ---------------- Kernel 2: Polyakov loops (line-shared LDS) -> W ch 6..9 ----
// Block = 256 threads = 16 lines x 16 rotations. The 16 threads of a line
// cooperatively stage the line's 16 link matrices in LDS (U read ONCE from
// global), then each thread computes its cyclic product from LDS.
template <typename WT>
__global__ __launch_bounds__(256) void poly_kernel(const float* __restrict__ Ure,
                                                   const float* __restrict__ Uim,
                                                   WT* __restrict__ W) {
    __shared__ float2 sm[16 * LSZ * 9];   // 16 lines * 16 matrices * 9 cplx = 18.4 KB

    int c = threadIdx.x & 15;             // position along line / rotation
    int l = threadIdx.x >> 4;             // local line 0..15
    int line_global = blockIdx.x * 16 + l;
    int mu   = line_global / NLINE_PER_DIR;        // 0..3, block-uniform
    int lidx = line_global - mu * NLINE_PER_DIR;   // 0..8191

    int sh   = 12 - 4 * mu;
    int low  = lidx & ((1 << sh) - 1);
    int high = lidx >> sh;
    int s_base = (high << (sh + 4)) | low;         // line base site (coord_mu = 0)

    // stage my matrix: site with coord_mu = c
    int sc = s_base | (c << sh);
    long off = (long)(sc * 4 + mu) * 9;
    float2* mym = &sm[(l * LSZ + c) * 9];
#pragma unroll
    for (int e = 0; e < 9; e++) mym[e] = make_float2(Ure[off + e], Uim[off + e]);
    __syncthreads();

    // P(c) = M[c] * M[c+1] * ... * M[c+15]  (cyclic)
    M3 P;
    {
        const float2* m0 = &sm[(l * LSZ + c) * 9];
#pragma unroll
        for (int e = 0; e < 9; e++) { float2 v = m0[e]; P.re[e] = v.x; P.im[e] = v.y; }
    }
    for (int step = 1; step < LSZ; step++) {
        const float2* mn = &sm[(l * LSZ + ((c + step) & 15)) * 9];
        M3 Un, T;
#pragma unroll
        for (int e = 0; e < 9; e++) { float2 v = mn[e]; Un.re[e] = v.x; Un.im[e] = v.y; }
        mulM(T, P, Un);
        P = T;
    }

    long base = ((long)sc * NIN + 6 + mu) * 9;
#pragma unroll
    for (int e = 0; e < 9; e++) w_store(W, base + e, P.re[e], P.im[e]);
}

// ---------------- Kernel 3: gauge-equivariant conv ----------------
// mode 0: interleaved (re,im) pairs; mode 1: planar [re][im]; mode 2: real only
template <typename WT>
__global__ __launch_bounds__(256) void conv_kernel(const float* __restrict__ Ure,
                                                   const float* __restrict__ Uim,
                                                   const float* __restrict__ omre,
                                                   const float* __restrict__ omim,
                                                   const WT* __restrict__ W,
                                                   float* __restrict__ out,
                                                   long out_limit, int mode) {
    __shared__ float2 som[NOUT * NIN * ND * 3];   // 7.5 KB
    for (int idx = threadIdx.x; idx < NOUT * NIN * ND * 3; idx += blockDim.x)
        som[idx] = make_float2(omre[idx], omim[idx]);
    __syncthreads();

    int tid = blockIdx.x * blockDim.x + threadIdx.x;
    int i = tid & 7;          // output channel
    int s = tid >> 3;         // site

    float accr[9] = {0,0,0,0,0,0,0,0,0};
    float acci[9] = {0,0,0,0,0,0,0,0,0};

    for (int mu = 0; mu < ND; mu++) {
        M3 Msum;
#pragma unroll
        for (int e = 0; e < 9; e++) { Msum.re[e] = 0.f; Msum.im[e] = 0.f; }

        for (int kk = 0; kk < 3; kk++) {            // k = kk-1
            int nb = shift_site(s, mu, kk - 1);
            long wbase = (long)nb * (NIN * 9);
            for (int j = 0; j < NIN; j++) {
                float2 om = som[((i * NIN + j) * ND + mu) * 3 + kk];
#pragma unroll
                for (int e = 0; e < 9; e++) {
                    float2 w = w_load(W, wbase + j * 9 + e);
                    Msum.re[e] = fmaf(om.x, w.x, Msum.re[e]);
                    Msum.re[e] = fmaf(-om.y, w.y, Msum.re[e]);
                    Msum.im[e] = fmaf(om.x, w.y, Msum.im[e]);
                    Msum.im[e] = fmaf(om.y, w.x, Msum.im[e]);
                }
            }
        }

        M3 A, T, R;
        loadM(A, Ure, Uim, (long)(s * 4 + mu) * 9);
        mulM(T, A, Msum);
        mulAdjM(R, T, A);
#pragma unroll
        for (int e = 0; e < 9; e++) { accr[e] += R.re[e]; acci[e] += R.im[e]; }
    }

    long cbase = (long)tid * 9;
    if (mode == 0) {
        long base = cbase * 2;
        if (base + 18 <= out_limit) {
            float2* op = (float2*)(out + base);
#pragma unroll
            for (int e = 0; e < 9; e++) op[e] = make_float2(accr[e], acci[e]);
        }
    } else if (mode == 1) {
        if (cbase + 9 <= NCPLX && NCPLX + cbase + 9 <= out_limit) {
#pragma unroll
            for (int e = 0; e < 9; e++) {
                out[cbase + e]         = accr[e];
                out[NCPLX + cbase + e] = acci[e];
            }
        }
    } else {
        if (cbase + 9 <= out_limit) {
#pragma unroll
            for (int e = 0; e < 9; e++) out[cbase + e] = accr[e];
        }
    }
}

extern "C" void kernel_launch(void* const* d_in, const int* in_sizes, int n_in,
                              void* d_out, int out_size, void* d_ws, size_t ws_size,
                              hipStream_t stream) {
    const float* Ure  = (const float*)d_in[0];
    const float* Uim  = (const float*)d_in[1];
    const float* omre = (const float*)d_in[2];
    const float* omim = (const float*)d_in[3];
    float* out = (float*)d_out;
    long out_limit = (long)out_size;

    int mode;
    if (out_size == (int)NCPLX)            mode = 2;
    else if (out_size == (int)(2 * NCPLX)) mode = 1;
    else                                   mode = 0;

    const size_t needA = (size_t)NSITE * NIN * 9 * sizeof(float2);  // 94.4 MB
    const size_t needB = (size_t)NSITE * NIN * 9 * sizeof(u32);     // 47.2 MB

    if (ws_size >= needA) {
        float2* W = (float2*)d_ws;
        plaq_kernel<float2><<<NSITE * 6 / 256, 256, 0, stream>>>(Ure, Uim, W);
        poly_kernel<float2><<<NSITE * 4 / 256, 256, 0, stream>>>(Ure, Uim, W);
        conv_kernel<float2><<<NSITE * 8 / 256, 256, 0, stream>>>(Ure, Uim, omre, omim, W, out, out_limit, mode);
    } else if (ws_size >= needB) {
        u32* W = (u32*)d_ws;
        plaq_kernel<u32><<<NSITE * 6 / 256, 256, 0, stream>>>(Ure, Uim, W);
        poly_kernel<u32><<<NSITE * 4 / 256, 256, 0, stream>>>(Ure, Uim, W);
        conv_kernel<u32><<<NSITE * 8 / 256, 256, 0, stream>>>(Ure, Uim, omre, omim, W, out, out_limit, mode);
    }
}

// Round 5
// 498.324 us; speedup vs baseline: 2.2962x; 1.0632x over previous
//
#include <hip/hip_runtime.h>

#define LSZ   16
#define NBATCH 2
#define NSITE (NBATCH*LSZ*LSZ*LSZ*LSZ)   // 131072
#define NIN   10
#define NOUT  8
#define ND    4
#define NCPLX ((long)NSITE * NOUT * 9)   // 9,437,184 complex output elements
#define NLINE_PER_DIR (NSITE / LSZ)      // 8192
#define NLINK (NSITE * ND)               // 524288
#define WSTRIDE 108                      // u32 per site: 9 e-rows * 12 j-slots (10 used)

typedef unsigned int u32;

struct M3 { float re[9]; float im[9]; };

// bf16 pack helpers: u32 = bf16(re) | bf16(im)<<16
__device__ __forceinline__ unsigned short f2bf(float x) {
    u32 u = __float_as_uint(x);
    u32 r = (u + 0x7fffu + ((u >> 16) & 1u)) >> 16;   // RNE
    return (unsigned short)r;
}
__device__ __forceinline__ u32 packbf(float re, float im) {
    return (u32)f2bf(re) | ((u32)f2bf(im) << 16);
}

__device__ __forceinline__ void loadM2(M3& m, const float2* __restrict__ U2, long link) {
    const float2* p = U2 + link * 9;
#pragma unroll
    for (int e = 0; e < 9; e++) { float2 v = p[e]; m.re[e] = v.x; m.im[e] = v.y; }
}

// o = a * b
__device__ __forceinline__ void mulM(M3& o, const M3& a, const M3& b) {
#pragma unroll
    for (int r = 0; r < 3; r++) {
#pragma unroll
        for (int c = 0; c < 3; c++) {
            float xr = 0.f, xi = 0.f;
#pragma unroll
            for (int k = 0; k < 3; k++) {
                float ar = a.re[r*3+k], ai = a.im[r*3+k];
                float br = b.re[k*3+c], bi = b.im[k*3+c];
                xr = fmaf(ar, br, xr); xr = fmaf(-ai, bi, xr);
                xi = fmaf(ar, bi, xi); xi = fmaf(ai, br, xi);
            }
            o.re[r*3+c] = xr; o.im[r*3+c] = xi;
        }
    }
}

// o = a * b^H
__device__ __forceinline__ void mulAdjM(M3& o, const M3& a, const M3& b) {
#pragma unroll
    for (int r = 0; r < 3; r++) {
#pragma unroll
        for (int c = 0; c < 3; c++) {
            float xr = 0.f, xi = 0.f;
#pragma unroll
            for (int k = 0; k < 3; k++) {
                float ar = a.re[r*3+k], ai = a.im[r*3+k];
                float br = b.re[c*3+k], bi = b.im[c*3+k];
                xr = fmaf(ar, br, xr); xr = fmaf(ai, bi, xr);
                xi = fmaf(ai, br, xi); xi = fmaf(-ar, bi, xi);
            }
            o.re[r*3+c] = xr; o.im[r*3+c] = xi;
        }
    }
}

// site s = b*65536 + x*4096 + y*256 + z*16 + t ; mu: 0->x,1->y,2->z,3->t
__device__ __forceinline__ int shift_site(int s, int mu, int k) {
    int sh = 12 - 4 * mu;
    int c  = (s >> sh) & 15;
    int nc = (c + k) & 15;
    return (s & ~(15 << sh)) | (nc << sh);
}

// -------- Kernel 0: repack U (separate re/im planes) -> interleaved float2 --------
__global__ __launch_bounds__(256) void repack_kernel(const float* __restrict__ Ure,
                                                     const float* __restrict__ Uim,
                                                     float2* __restrict__ U2) {
    int t = blockIdx.x * blockDim.x + threadIdx.x;   // over NLINK*9 = 4,718,592
    U2[t] = make_float2(Ure[t], Uim[t]);
}

// ---------------- Kernel 1: plaquettes -> W channels 0..5 ----------------
__global__ __launch_bounds__(256) void plaq_kernel(const float2* __restrict__ U2,
                                                   u32* __restrict__ W) {
    int tid = blockIdx.x * blockDim.x + threadIdx.x;
    int p = tid / NSITE;            // 0..5, wave-uniform
    int s = tid - p * NSITE;
    int mu = (p < 3) ? 0 : ((p < 5) ? 1 : 2);
    int nu = (mu == 0) ? (p + 1) : ((mu == 1) ? (p - 1) : 3);

    M3 Umu, Unu, Unu_f, Umu_f, T1, T2, P;
    loadM2(Umu, U2, (long)s * 4 + mu);
    loadM2(Unu, U2, (long)s * 4 + nu);
    int spmu = shift_site(s, mu, 1);
    int spnu = shift_site(s, nu, 1);
    loadM2(Unu_f, U2, (long)spmu * 4 + nu);   // U_nu(x+mu)
    loadM2(Umu_f, U2, (long)spnu * 4 + mu);   // U_mu(x+nu)

    mulM(T1, Umu, Unu_f);
    mulAdjM(T2, T1, Umu_f);
    mulAdjM(P, T2, Unu);

    u32* Wp = W + (long)s * WSTRIDE;
#pragma unroll
    for (int e = 0; e < 9; e++) Wp[e * 12 + p] = packbf(P.re[e], P.im[e]);
}

// ---------------- Kernel 2: Polyakov loops (line-shared LDS) -> W ch 6..9 ----
__global__ __launch_bounds__(256) void poly_kernel(const float2* __restrict__ U2,
                                                   u32* __restrict__ W) {
    __shared__ float2 sm[16 * LSZ * 9];   // 18.4 KB

    int c = threadIdx.x & 15;             // position along line / rotation
    int l = threadIdx.x >> 4;             // local line 0..15
    int line_global = blockIdx.x * 16 + l;
    int mu   = line_global / NLINE_PER_DIR;        // 0..3, block-uniform
    int lidx = line_global - mu * NLINE_PER_DIR;   // 0..8191

    int sh   = 12 - 4 * mu;
    int low  = lidx & ((1 << sh) - 1);
    int high = lidx >> sh;
    int s_base = (high << (sh + 4)) | low;         // line base site (coord_mu = 0)

    int sc = s_base | (c << sh);
    const float2* src = U2 + ((long)(sc * 4 + mu)) * 9;
    float2* mym = &sm[(l * LSZ + c) * 9];
#pragma unroll
    for (int e = 0; e < 9; e++) mym[e] = src[e];
    __syncthreads();

    M3 P;
    {
        const float2* m0 = &sm[(l * LSZ + c) * 9];
#pragma unroll
        for (int e = 0; e < 9; e++) { float2 v = m0[e]; P.re[e] = v.x; P.im[e] = v.y; }
    }
    for (int step = 1; step < LSZ; step++) {
        const float2* mn = &sm[(l * LSZ + ((c + step) & 15)) * 9];
        M3 Un, T;
#pragma unroll
        for (int e = 0; e < 9; e++) { float2 v = mn[e]; Un.re[e] = v.x; Un.im[e] = v.y; }
        mulM(T, P, Un);
        P = T;
    }

    u32* Wp = W + (long)sc * WSTRIDE;
#pragma unroll
    for (int e = 0; e < 9; e++) Wp[e * 12 + 6 + mu] = packbf(P.re[e], P.im[e]);
}

// ---------------- Kernel 3: gauge-equivariant conv ----------------
// MODE 0: interleaved (re,im); MODE 1: planar [re][im]; MODE 2: real only
template <int MODE>
__global__ __launch_bounds__(256) void conv_kernel(const float2* __restrict__ U2,
                                                   const u32* __restrict__ W,
                                                   const float* __restrict__ omre,
                                                   const float* __restrict__ omim,
                                                   float* __restrict__ out) {
    // som[(mk*10 + j)*8 + i] — i fastest => conflict-free broadcast reads
    __shared__ float2 som[12 * NIN * 8];   // 960 * 8B = 7.5 KB
    for (int t = threadIdx.x; t < 12 * NIN * 8; t += blockDim.x) {
        int i  = t & 7;
        int j  = (t >> 3) % NIN;
        int mk = (t >> 3) / NIN;
        int mu = mk / 3, kk = mk % 3;
        int oidx = ((i * NIN + j) * ND + mu) * 3 + kk;
        som[t] = make_float2(omre[oidx], omim[oidx]);
    }
    __syncthreads();

    int tid = blockIdx.x * blockDim.x + threadIdx.x;
    int i = tid & 7;          // output channel
    int s = tid >> 3;         // site

    float accr[9] = {0,0,0,0,0,0,0,0,0};
    float acci[9] = {0,0,0,0,0,0,0,0,0};

    for (int mu = 0; mu < ND; mu++) {
        float mr[9] = {0,0,0,0,0,0,0,0,0};
        float mi[9] = {0,0,0,0,0,0,0,0,0};

        for (int kk = 0; kk < 3; kk++) {
            int nb = shift_site(s, mu, kk - 1);
            const uint4* Wb = (const uint4*)(W + (long)nb * WSTRIDE);  // 16B-aligned (432B blocks)
            const float2* omp = &som[((mu * 3 + kk) * NIN) * 8 + i];
            float ore[NIN], oim[NIN];
#pragma unroll
            for (int j = 0; j < NIN; j++) { float2 v = omp[j * 8]; ore[j] = v.x; oim[j] = v.y; }

#pragma unroll
            for (int e = 0; e < 9; e++) {
                uint4 a = Wb[e * 3 + 0];
                uint4 b = Wb[e * 3 + 1];
                uint4 cv = Wb[e * 3 + 2];
                u32 wv[NIN] = {a.x, a.y, a.z, a.w, b.x, b.y, b.z, b.w, cv.x, cv.y};
                float sr = mr[e], si = mi[e];
#pragma unroll
                for (int j = 0; j < NIN; j++) {
                    float wr = __uint_as_float(wv[j] << 16);
                    float wi = __uint_as_float(wv[j] & 0xffff0000u);
                    sr = fmaf(ore[j], wr, sr); sr = fmaf(-oim[j], wi, sr);
                    si = fmaf(ore[j], wi, si); si = fmaf(oim[j], wr, si);
                }
                mr[e] = sr; mi[e] = si;
            }
        }

        // epilogue: out += A * Msum * A^H
        M3 A;
        loadM2(A, U2, (long)s * 4 + mu);
        M3 T;
#pragma unroll
        for (int r = 0; r < 3; r++) {
#pragma unroll
            for (int c = 0; c < 3; c++) {
                float xr = 0.f, xi = 0.f;
#pragma unroll
                for (int k = 0; k < 3; k++) {
                    float ar = A.re[r*3+k], ai = A.im[r*3+k];
                    float br = mr[k*3+c],  bi = mi[k*3+c];
                    xr = fmaf(ar, br, xr); xr = fmaf(-ai, bi, xr);
                    xi = fmaf(ar, bi, xi); xi = fmaf(ai, br, xi);
                }
                T.re[r*3+c] = xr; T.im[r*3+c] = xi;
            }
        }
#pragma unroll
        for (int r = 0; r < 3; r++) {
#pragma unroll
            for (int c = 0; c < 3; c++) {
                float xr = 0.f, xi = 0.f;
#pragma unroll
                for (int k = 0; k < 3; k++) {
                    float ar = T.re[r*3+k], ai = T.im[r*3+k];
                    float br = A.re[c*3+k], bi = A.im[c*3+k];
                    xr = fmaf(ar, br, xr); xr = fmaf(ai, bi, xr);
                    if (MODE != 2) { xi = fmaf(ai, br, xi); xi = fmaf(-ar, bi, xi); }
                }
                accr[r*3+c] += xr;
                if (MODE != 2) acci[r*3+c] += xi;
            }
        }
    }

    long cbase = (long)tid * 9;
    if (MODE == 0) {
        float2* op = (float2*)(out + cbase * 2);
#pragma unroll
        for (int e = 0; e < 9; e++) op[e] = make_float2(accr[e], acci[e]);
    } else if (MODE == 1) {
#pragma unroll
        for (int e = 0; e < 9; e++) {
            out[cbase + e]         = accr[e];
            out[NCPLX + cbase + e] = acci[e];
        }
    } else {
#pragma unroll
        for (int e = 0; e < 9; e++) out[cbase + e] = accr[e];
    }
}

extern "C" void kernel_launch(void* const* d_in, const int* in_sizes, int n_in,
                              void* d_out, int out_size, void* d_ws, size_t ws_size,
                              hipStream_t stream) {
    const float* Ure  = (const float*)d_in[0];
    const float* Uim  = (const float*)d_in[1];
    const float* omre = (const float*)d_in[2];
    const float* omim = (const float*)d_in[3];
    float* out = (float*)d_out;

    // ws layout: [W bf16: NSITE*108*4 = 56,623,104 B][U2: NLINK*9*8 = 37,748,736 B]
    const size_t wBytes  = (size_t)NSITE * WSTRIDE * sizeof(u32);
    const size_t u2Bytes = (size_t)NLINK * 9 * sizeof(float2);
    if (ws_size < wBytes + u2Bytes) return;   // R3/R4 proved ws >= 94.4 MB (fp32 path ran)

    u32*    W  = (u32*)d_ws;
    float2* U2 = (float2*)((char*)d_ws + wBytes);

    repack_kernel<<<(NLINK * 9) / 256, 256, 0, stream>>>(Ure, Uim, U2);
    plaq_kernel<<<NSITE * 6 / 256, 256, 0, stream>>>(U2, W);
    poly_kernel<<<NSITE * 4 / (16 * 16), 256, 0, stream>>>(U2, W);

    if (out_size == (int)NCPLX)
        conv_kernel<2><<<NSITE * 8 / 256, 256, 0, stream>>>(U2, W, omre, omim, out);
    else if (out_size == (int)(2 * NCPLX))
        conv_kernel<1><<<NSITE * 8 / 256, 256, 0, stream>>>(U2, W, omre, omim, out);
    else
        conv_kernel<0><<<NSITE * 8 / 256, 256, 0, stream>>>(U2, W, omre, omim, out);
}

// Round 6
// 379.212 us; speedup vs baseline: 3.0174x; 1.3141x over previous
//
#include <hip/hip_runtime.h>

#define LSZ   16
#define NBATCH 2
#define NSITE (NBATCH*LSZ*LSZ*LSZ*LSZ)   // 131072
#define NIN   10
#define NOUT  8
#define ND    4
#define NCPLX ((long)NSITE * NOUT * 9)   // 9,437,184 complex output elements
#define NLINE_PER_DIR (NSITE / LSZ)      // 8192
#define NLINK (NSITE * ND)               // 524288
#define WSTRIDE 108                      // u32 per site: 9 e-rows * 12 ch-slots (10 used)

typedef unsigned int u32;

struct M3 { float re[9]; float im[9]; };

// bf16 pack helpers: u32 = bf16(re) | bf16(im)<<16
__device__ __forceinline__ unsigned short f2bf(float x) {
    u32 u = __float_as_uint(x);
    u32 r = (u + 0x7fffu + ((u >> 16) & 1u)) >> 16;   // RNE
    return (unsigned short)r;
}
__device__ __forceinline__ u32 packbf(float re, float im) {
    return (u32)f2bf(re) | ((u32)f2bf(im) << 16);
}

__device__ __forceinline__ void loadM2(M3& m, const float2* __restrict__ U2, long link) {
    const float2* p = U2 + link * 9;
#pragma unroll
    for (int e = 0; e < 9; e++) { float2 v = p[e]; m.re[e] = v.x; m.im[e] = v.y; }
}

// o = a * b
__device__ __forceinline__ void mulM(M3& o, const M3& a, const M3& b) {
#pragma unroll
    for (int r = 0; r < 3; r++) {
#pragma unroll
        for (int c = 0; c < 3; c++) {
            float xr = 0.f, xi = 0.f;
#pragma unroll
            for (int k = 0; k < 3; k++) {
                float ar = a.re[r*3+k], ai = a.im[r*3+k];
                float br = b.re[k*3+c], bi = b.im[k*3+c];
                xr = fmaf(ar, br, xr); xr = fmaf(-ai, bi, xr);
                xi = fmaf(ar, bi, xi); xi = fmaf(ai, br, xi);
            }
            o.re[r*3+c] = xr; o.im[r*3+c] = xi;
        }
    }
}

// o = a * b^H
__device__ __forceinline__ void mulAdjM(M3& o, const M3& a, const M3& b) {
#pragma unroll
    for (int r = 0; r < 3; r++) {
#pragma unroll
        for (int c = 0; c < 3; c++) {
            float xr = 0.f, xi = 0.f;
#pragma unroll
            for (int k = 0; k < 3; k++) {
                float ar = a.re[r*3+k], ai = a.im[r*3+k];
                float br = b.re[c*3+k], bi = b.im[c*3+k];
                xr = fmaf(ar, br, xr); xr = fmaf(ai, bi, xr);
                xi = fmaf(ai, br, xi); xi = fmaf(-ar, bi, xi);
            }
            o.re[r*3+c] = xr; o.im[r*3+c] = xi;
        }
    }
}

// site s = b*65536 + x*4096 + y*256 + z*16 + t ; mu: 0->x,1->y,2->z,3->t
__device__ __forceinline__ int shift_site(int s, int mu, int k) {
    int sh = 12 - 4 * mu;
    int c  = (s >> sh) & 15;
    int nc = (c + k) & 15;
    return (s & ~(15 << sh)) | (nc << sh);
}

// -------- Kernel 0: repack U (planar re/im) -> interleaved float2 --------
__global__ __launch_bounds__(256) void repack_kernel(const float* __restrict__ Ure,
                                                     const float* __restrict__ Uim,
                                                     float2* __restrict__ U2) {
    int t = blockIdx.x * blockDim.x + threadIdx.x;   // over NLINK*9
    U2[t] = make_float2(Ure[t], Uim[t]);
}

// ---------------- Kernel 1: Polyakov loops -> compact T (coalesced) ----------
// T layout: [line_global][e][c] u32, line_global = mu*8192 + lidx. Block writes
// 16 lines x 9 e x 16 c = 9216 B contiguous; each store instr fills whole lines.
__global__ __launch_bounds__(256) void poly_kernel(const float2* __restrict__ U2,
                                                   u32* __restrict__ T) {
    __shared__ float2 sm[16 * LSZ * 9];   // 18.4 KB

    int c = threadIdx.x & 15;             // position along line / rotation
    int l = threadIdx.x >> 4;             // local line 0..15
    int line_global = blockIdx.x * 16 + l;
    int mu   = line_global / NLINE_PER_DIR;        // 0..3, block-uniform
    int lidx = line_global - mu * NLINE_PER_DIR;   // 0..8191

    int sh   = 12 - 4 * mu;
    int low  = lidx & ((1 << sh) - 1);
    int high = lidx >> sh;
    int s_base = (high << (sh + 4)) | low;         // line base site (coord_mu = 0)

    int sc = s_base | (c << sh);
    const float2* src = U2 + ((long)(sc * 4 + mu)) * 9;
    float2* mym = &sm[(l * LSZ + c) * 9];
#pragma unroll
    for (int e = 0; e < 9; e++) mym[e] = src[e];
    __syncthreads();

    M3 P;
    {
        const float2* m0 = &sm[(l * LSZ + c) * 9];
#pragma unroll
        for (int e = 0; e < 9; e++) { float2 v = m0[e]; P.re[e] = v.x; P.im[e] = v.y; }
    }
    for (int step = 1; step < LSZ; step++) {
        const float2* mn = &sm[(l * LSZ + ((c + step) & 15)) * 9];
        M3 Un, Tm;
#pragma unroll
        for (int e = 0; e < 9; e++) { float2 v = mn[e]; Un.re[e] = v.x; Un.im[e] = v.y; }
        mulM(Tm, P, Un);
        P = Tm;
    }

    u32* Tp = T + ((long)line_global * 9) * 16 + c;
#pragma unroll
    for (int e = 0; e < 9; e++) Tp[e * 16] = packbf(P.re[e], P.im[e]);
}

// ------- Kernel 2: plaquettes + merge-poly -> W, fully coalesced writes -------
// Block = 192 threads = 32 sites x 6 plaquettes. Each thread computes one
// plaquette into an LDS site-block image [32][108]; poly channels gathered
// from T into the same image; then 864 coalesced uint4 stores.
__global__ __launch_bounds__(192) void plaq_merge_kernel(const float2* __restrict__ U2,
                                                         const u32* __restrict__ T,
                                                         u32* __restrict__ W) {
    __shared__ u32 sw[32 * WSTRIDE];   // 13824 B

    int p  = threadIdx.x >> 5;          // 0..5 (half-wave uniform)
    int ls = threadIdx.x & 31;          // local site 0..31
    int s0 = blockIdx.x * 32;
    int s  = s0 + ls;

    int mu = (p < 3) ? 0 : ((p < 5) ? 1 : 2);
    int nu = (mu == 0) ? (p + 1) : ((mu == 1) ? (p - 1) : 3);

    M3 Umu, Unu, Unu_f, Umu_f, T1, T2, P;
    loadM2(Umu, U2, (long)s * 4 + mu);
    loadM2(Unu, U2, (long)s * 4 + nu);
    int spmu = shift_site(s, mu, 1);
    int spnu = shift_site(s, nu, 1);
    loadM2(Unu_f, U2, (long)spmu * 4 + nu);   // U_nu(x+mu)
    loadM2(Umu_f, U2, (long)spnu * 4 + mu);   // U_mu(x+nu)

    mulM(T1, Umu, Unu_f);
    mulAdjM(T2, T1, Umu_f);
    mulAdjM(P, T2, Unu);

#pragma unroll
    for (int e = 0; e < 9; e++) sw[ls * WSTRIDE + e * 12 + p] = packbf(P.re[e], P.im[e]);

    // gather poly channels from T: 32 sites x 4 mu x 9 e = 1152 u32
    for (int it = threadIdx.x; it < 32 * 4 * 9; it += 192) {
        int ls2 = it / 36;
        int r   = it - ls2 * 36;
        int mu2 = r / 9;
        int e2  = r - mu2 * 9;
        int s2  = s0 + ls2;
        int sh  = 12 - 4 * mu2;
        int c   = (s2 >> sh) & 15;
        int low = s2 & ((1 << sh) - 1);
        int rest = s2 >> (sh + 4);
        int lidx = (rest << sh) | low;
        long lg  = (long)mu2 * NLINE_PER_DIR + lidx;
        sw[ls2 * WSTRIDE + e2 * 12 + 6 + mu2] = T[(lg * 9 + e2) * 16 + c];
    }
    __syncthreads();

    // coalesced block write: 32 full site-blocks = 864 uint4
    uint4* Wv = (uint4*)(W + (long)s0 * WSTRIDE);
    const uint4* sv = (const uint4*)sw;
    for (int it = threadIdx.x; it < 32 * WSTRIDE / 4; it += 192)
        Wv[it] = sv[it];
}

// ---------------- Kernel 3: gauge-equivariant conv ----------------
// MODE 0: interleaved (re,im); MODE 1: planar [re][im]; MODE 2: real only
template <int MODE>
__global__ __launch_bounds__(256) void conv_kernel(const float2* __restrict__ U2,
                                                   const u32* __restrict__ W,
                                                   const float* __restrict__ omre,
                                                   const float* __restrict__ omim,
                                                   float* __restrict__ out) {
    // som[(mk*10 + j)*8 + i] — i fastest => conflict-free broadcast reads
    __shared__ float2 som[12 * NIN * 8];   // 7.5 KB
    for (int t = threadIdx.x; t < 12 * NIN * 8; t += blockDim.x) {
        int i  = t & 7;
        int j  = (t >> 3) % NIN;
        int mk = (t >> 3) / NIN;
        int mu = mk / 3, kk = mk % 3;
        int oidx = ((i * NIN + j) * ND + mu) * 3 + kk;
        som[t] = make_float2(omre[oidx], omim[oidx]);
    }
    __syncthreads();

    int tid = blockIdx.x * blockDim.x + threadIdx.x;
    int i = tid & 7;          // output channel
    int s = tid >> 3;         // site

    float accr[9] = {0,0,0,0,0,0,0,0,0};
    float acci[9] = {0,0,0,0,0,0,0,0,0};

    for (int mu = 0; mu < ND; mu++) {
        float mr[9] = {0,0,0,0,0,0,0,0,0};
        float mi[9] = {0,0,0,0,0,0,0,0,0};

        for (int kk = 0; kk < 3; kk++) {
            int nb = shift_site(s, mu, kk - 1);
            const uint4* Wb = (const uint4*)(W + (long)nb * WSTRIDE);
            const float2* omp = &som[((mu * 3 + kk) * NIN) * 8 + i];
            float ore[NIN], oim[NIN];
#pragma unroll
            for (int j = 0; j < NIN; j++) { float2 v = omp[j * 8]; ore[j] = v.x; oim[j] = v.y; }

#pragma unroll
            for (int e = 0; e < 9; e++) {
                uint4 a = Wb[e * 3 + 0];
                uint4 b = Wb[e * 3 + 1];
                uint4 cv = Wb[e * 3 + 2];
                u32 wv[NIN] = {a.x, a.y, a.z, a.w, b.x, b.y, b.z, b.w, cv.x, cv.y};
                float sr = mr[e], si = mi[e];
#pragma unroll
                for (int j = 0; j < NIN; j++) {
                    float wr = __uint_as_float(wv[j] << 16);
                    float wi = __uint_as_float(wv[j] & 0xffff0000u);
                    sr = fmaf(ore[j], wr, sr); sr = fmaf(-oim[j], wi, sr);
                    si = fmaf(ore[j], wi, si); si = fmaf(oim[j], wr, si);
                }
                mr[e] = sr; mi[e] = si;
            }
        }

        // epilogue: out += A * Msum * A^H
        M3 A;
        loadM2(A, U2, (long)s * 4 + mu);
        M3 Tm;
#pragma unroll
        for (int r = 0; r < 3; r++) {
#pragma unroll
            for (int c = 0; c < 3; c++) {
                float xr = 0.f, xi = 0.f;
#pragma unroll
                for (int k = 0; k < 3; k++) {
                    float ar = A.re[r*3+k], ai = A.im[r*3+k];
                    float br = mr[k*3+c],  bi = mi[k*3+c];
                    xr = fmaf(ar, br, xr); xr = fmaf(-ai, bi, xr);
                    xi = fmaf(ar, bi, xi); xi = fmaf(ai, br, xi);
                }
                Tm.re[r*3+c] = xr; Tm.im[r*3+c] = xi;
            }
        }
#pragma unroll
        for (int r = 0; r < 3; r++) {
#pragma unroll
            for (int c = 0; c < 3; c++) {
                float xr = 0.f, xi = 0.f;
#pragma unroll
                for (int k = 0; k < 3; k++) {
                    float ar = Tm.re[r*3+k], ai = Tm.im[r*3+k];
                    float br = A.re[c*3+k], bi = A.im[c*3+k];
                    xr = fmaf(ar, br, xr); xr = fmaf(ai, bi, xr);
                    if (MODE != 2) { xi = fmaf(ai, br, xi); xi = fmaf(-ar, bi, xi); }
                }
                accr[r*3+c] += xr;
                if (MODE != 2) acci[r*3+c] += xi;
            }
        }
    }

    long cbase = (long)tid * 9;
    if (MODE == 0) {
        float2* op = (float2*)(out + cbase * 2);
#pragma unroll
        for (int e = 0; e < 9; e++) op[e] = make_float2(accr[e], acci[e]);
    } else if (MODE == 1) {
#pragma unroll
        for (int e = 0; e < 9; e++) {
            out[cbase + e]         = accr[e];
            out[NCPLX + cbase + e] = acci[e];
        }
    } else {
#pragma unroll
        for (int e = 0; e < 9; e++) out[cbase + e] = accr[e];
    }
}

extern "C" void kernel_launch(void* const* d_in, const int* in_sizes, int n_in,
                              void* d_out, int out_size, void* d_ws, size_t ws_size,
                              hipStream_t stream) {
    const float* Ure  = (const float*)d_in[0];
    const float* Uim  = (const float*)d_in[1];
    const float* omre = (const float*)d_in[2];
    const float* omim = (const float*)d_in[3];
    float* out = (float*)d_out;

    // ws layout: [W bf16: 56,623,104 B][U2: 37,748,736 B]  (= 94.4 MB, proven)
    const size_t wBytes  = (size_t)NSITE * WSTRIDE * sizeof(u32);
    const size_t u2Bytes = (size_t)NLINK * 9 * sizeof(float2);
    if (ws_size < wBytes + u2Bytes) return;

    u32*    W  = (u32*)d_ws;
    float2* U2 = (float2*)((char*)d_ws + wBytes);
    // T (18.87 MB) lives in d_out (37.7 MB): written by poly, read by plaq_merge,
    // fully overwritten by conv afterwards. Stream-ordered => no hazard.
    u32*    T  = (u32*)d_out;

    repack_kernel<<<(NLINK * 9) / 256, 256, 0, stream>>>(Ure, Uim, U2);
    poly_kernel<<<NSITE * 4 / (16 * 16), 256, 0, stream>>>(U2, T);
    plaq_merge_kernel<<<NSITE / 32, 192, 0, stream>>>(U2, T, W);

    if (out_size == (int)NCPLX)
        conv_kernel<2><<<NSITE * 8 / 256, 256, 0, stream>>>(U2, W, omre, omim, out);
    else if (out_size == (int)(2 * NCPLX))
        conv_kernel<1><<<NSITE * 8 / 256, 256, 0, stream>>>(U2, W, omre, omim, out);
    else
        conv_kernel<0><<<NSITE * 8 / 256, 256, 0, stream>>>(U2, W, omre, omim, out);
}

// Round 7
// 371.174 us; speedup vs baseline: 3.0828x; 1.0217x over previous
//
#include <hip/hip_runtime.h>

#define LSZ   16
#define NBATCH 2
#define NSITE (NBATCH*LSZ*LSZ*LSZ*LSZ)   // 131072
#define NIN   10
#define NOUT  8
#define ND    4
#define NCPLX ((long)NSITE * NOUT * 9)   // 9,437,184 complex output elements
#define NLINE_PER_DIR (NSITE / LSZ)      // 8192
#define NLINK (NSITE * ND)               // 524288
#define WSTRIDE 108                      // u32 per site: 9 e-rows * 12 ch-slots (10 used)

typedef unsigned int u32;

struct M3 { float re[9]; float im[9]; };

// bf16 pack helpers: u32 = bf16(re) | bf16(im)<<16
__device__ __forceinline__ unsigned short f2bf(float x) {
    u32 u = __float_as_uint(x);
    u32 r = (u + 0x7fffu + ((u >> 16) & 1u)) >> 16;   // RNE
    return (unsigned short)r;
}
__device__ __forceinline__ u32 packbf(float re, float im) {
    return (u32)f2bf(re) | ((u32)f2bf(im) << 16);
}

#if __has_builtin(__builtin_amdgcn_fdot2_f32_bf16)
#define CONV_DOT2 1
typedef __bf16 bf16x2 __attribute__((ext_vector_type(2)));
__device__ __forceinline__ bf16x2 as_b2(u32 v) {
    union { u32 u; bf16x2 b; } x; x.u = v; return x.b;
}
// complex MAC: w = (wr,wi) bf16 pair; oa = (or,-oi); ob = (oi,or)
__device__ __forceinline__ void cdot(u32 w, u32 oa, u32 ob, float& sr, float& si) {
    sr = __builtin_amdgcn_fdot2_f32_bf16(as_b2(w), as_b2(oa), sr, false);
    si = __builtin_amdgcn_fdot2_f32_bf16(as_b2(w), as_b2(ob), si, false);
}
#else
#define CONV_DOT2 0
#endif

__device__ __forceinline__ void loadM2(M3& m, const float2* __restrict__ U2, long link) {
    const float2* p = U2 + link * 9;
#pragma unroll
    for (int e = 0; e < 9; e++) { float2 v = p[e]; m.re[e] = v.x; m.im[e] = v.y; }
}

// o = a * b
__device__ __forceinline__ void mulM(M3& o, const M3& a, const M3& b) {
#pragma unroll
    for (int r = 0; r < 3; r++) {
#pragma unroll
        for (int c = 0; c < 3; c++) {
            float xr = 0.f, xi = 0.f;
#pragma unroll
            for (int k = 0; k < 3; k++) {
                float ar = a.re[r*3+k], ai = a.im[r*3+k];
                float br = b.re[k*3+c], bi = b.im[k*3+c];
                xr = fmaf(ar, br, xr); xr = fmaf(-ai, bi, xr);
                xi = fmaf(ar, bi, xi); xi = fmaf(ai, br, xi);
            }
            o.re[r*3+c] = xr; o.im[r*3+c] = xi;
        }
    }
}

// o = a * b^H
__device__ __forceinline__ void mulAdjM(M3& o, const M3& a, const M3& b) {
#pragma unroll
    for (int r = 0; r < 3; r++) {
#pragma unroll
        for (int c = 0; c < 3; c++) {
            float xr = 0.f, xi = 0.f;
#pragma unroll
            for (int k = 0; k < 3; k++) {
                float ar = a.re[r*3+k], ai = a.im[r*3+k];
                float br = b.re[c*3+k], bi = b.im[c*3+k];
                xr = fmaf(ar, br, xr); xr = fmaf(ai, bi, xr);
                xi = fmaf(ai, br, xi); xi = fmaf(-ar, bi, xi);
            }
            o.re[r*3+c] = xr; o.im[r*3+c] = xi;
        }
    }
}

// site s = b*65536 + x*4096 + y*256 + z*16 + t ; mu: 0->x,1->y,2->z,3->t
__device__ __forceinline__ int shift_site(int s, int mu, int k) {
    int sh = 12 - 4 * mu;
    int c  = (s >> sh) & 15;
    int nc = (c + k) & 15;
    return (s & ~(15 << sh)) | (nc << sh);
}

// -------- Kernel 0: repack U (planar re/im) -> interleaved float2 --------
__global__ __launch_bounds__(256) void repack_kernel(const float* __restrict__ Ure,
                                                     const float* __restrict__ Uim,
                                                     float2* __restrict__ U2) {
    int t = blockIdx.x * blockDim.x + threadIdx.x;   // over NLINK*9
    U2[t] = make_float2(Ure[t], Uim[t]);
}

// ---------------- Kernel 1: Polyakov loops -> compact T (coalesced) ----------
__global__ __launch_bounds__(256) void poly_kernel(const float2* __restrict__ U2,
                                                   u32* __restrict__ T) {
    __shared__ float2 sm[16 * LSZ * 9];   // 18.4 KB

    int c = threadIdx.x & 15;
    int l = threadIdx.x >> 4;
    int line_global = blockIdx.x * 16 + l;
    int mu   = line_global / NLINE_PER_DIR;
    int lidx = line_global - mu * NLINE_PER_DIR;

    int sh   = 12 - 4 * mu;
    int low  = lidx & ((1 << sh) - 1);
    int high = lidx >> sh;
    int s_base = (high << (sh + 4)) | low;

    int sc = s_base | (c << sh);
    const float2* src = U2 + ((long)(sc * 4 + mu)) * 9;
    float2* mym = &sm[(l * LSZ + c) * 9];
#pragma unroll
    for (int e = 0; e < 9; e++) mym[e] = src[e];
    __syncthreads();

    M3 P;
    {
        const float2* m0 = &sm[(l * LSZ + c) * 9];
#pragma unroll
        for (int e = 0; e < 9; e++) { float2 v = m0[e]; P.re[e] = v.x; P.im[e] = v.y; }
    }
    for (int step = 1; step < LSZ; step++) {
        const float2* mn = &sm[(l * LSZ + ((c + step) & 15)) * 9];
        M3 Un, Tm;
#pragma unroll
        for (int e = 0; e < 9; e++) { float2 v = mn[e]; Un.re[e] = v.x; Un.im[e] = v.y; }
        mulM(Tm, P, Un);
        P = Tm;
    }

    u32* Tp = T + ((long)line_global * 9) * 16 + c;
#pragma unroll
    for (int e = 0; e < 9; e++) Tp[e * 16] = packbf(P.re[e], P.im[e]);
}

// ------- Kernel 2: plaquettes + merge-poly -> W, fully coalesced writes -------
__global__ __launch_bounds__(192) void plaq_merge_kernel(const float2* __restrict__ U2,
                                                         const u32* __restrict__ T,
                                                         u32* __restrict__ W) {
    __shared__ u32 sw[32 * WSTRIDE];   // 13824 B

    int p  = threadIdx.x >> 5;          // 0..5
    int ls = threadIdx.x & 31;          // local site
    int s0 = blockIdx.x * 32;
    int s  = s0 + ls;

    int mu = (p < 3) ? 0 : ((p < 5) ? 1 : 2);
    int nu = (mu == 0) ? (p + 1) : ((mu == 1) ? (p - 1) : 3);

    M3 Umu, Unu, Unu_f, Umu_f, T1, T2, P;
    loadM2(Umu, U2, (long)s * 4 + mu);
    loadM2(Unu, U2, (long)s * 4 + nu);
    int spmu = shift_site(s, mu, 1);
    int spnu = shift_site(s, nu, 1);
    loadM2(Unu_f, U2, (long)spmu * 4 + nu);
    loadM2(Umu_f, U2, (long)spnu * 4 + mu);

    mulM(T1, Umu, Unu_f);
    mulAdjM(T2, T1, Umu_f);
    mulAdjM(P, T2, Unu);

#pragma unroll
    for (int e = 0; e < 9; e++) sw[ls * WSTRIDE + e * 12 + p] = packbf(P.re[e], P.im[e]);

    for (int it = threadIdx.x; it < 32 * 4 * 9; it += 192) {
        int ls2 = it / 36;
        int r   = it - ls2 * 36;
        int mu2 = r / 9;
        int e2  = r - mu2 * 9;
        int s2  = s0 + ls2;
        int sh  = 12 - 4 * mu2;
        int c   = (s2 >> sh) & 15;
        int low = s2 & ((1 << sh) - 1);
        int rest = s2 >> (sh + 4);
        int lidx = (rest << sh) | low;
        long lg  = (long)mu2 * NLINE_PER_DIR + lidx;
        sw[ls2 * WSTRIDE + e2 * 12 + 6 + mu2] = T[(lg * 9 + e2) * 16 + c];
    }
    __syncthreads();

    uint4* Wv = (uint4*)(W + (long)s0 * WSTRIDE);
    const uint4* sv = (const uint4*)sw;
    for (int it = threadIdx.x; it < 32 * WSTRIDE / 4; it += 192)
        Wv[it] = sv[it];
}

// ---------------- Kernel 3: gauge-equivariant conv ----------------
// MODE 0: interleaved (re,im); MODE 1: planar [re][im]; MODE 2: real only
template <int MODE>
__global__ __launch_bounds__(256) void conv_kernel(const float2* __restrict__ U2,
                                                   const u32* __restrict__ W,
                                                   const float* __restrict__ omre,
                                                   const float* __restrict__ omim,
                                                   float* __restrict__ out) {
#if CONV_DOT2
    // som[(mk*10+j)*8 + i]: .x = bf16pair(or, -oi), .y = bf16pair(oi, or)
    __shared__ uint2 som[12 * NIN * 8];   // 7.5 KB
    for (int t = threadIdx.x; t < 12 * NIN * 8; t += blockDim.x) {
        int i  = t & 7;
        int j  = (t >> 3) % NIN;
        int mk = (t >> 3) / NIN;
        int mu = mk / 3, kk = mk % 3;
        int oidx = ((i * NIN + j) * ND + mu) * 3 + kk;
        float orv = omre[oidx], oiv = omim[oidx];
        som[t] = make_uint2(packbf(orv, -oiv), packbf(oiv, orv));
    }
#else
    __shared__ float2 som[12 * NIN * 8];   // 7.5 KB
    for (int t = threadIdx.x; t < 12 * NIN * 8; t += blockDim.x) {
        int i  = t & 7;
        int j  = (t >> 3) % NIN;
        int mk = (t >> 3) / NIN;
        int mu = mk / 3, kk = mk % 3;
        int oidx = ((i * NIN + j) * ND + mu) * 3 + kk;
        som[t] = make_float2(omre[oidx], omim[oidx]);
    }
#endif
    __syncthreads();

    int tid = blockIdx.x * blockDim.x + threadIdx.x;
    int i = tid & 7;          // output channel
    int s = tid >> 3;         // site

    float accr[9] = {0,0,0,0,0,0,0,0,0};
    float acci[9] = {0,0,0,0,0,0,0,0,0};

    for (int mu = 0; mu < ND; mu++) {
        float mr[9] = {0,0,0,0,0,0,0,0,0};
        float mi[9] = {0,0,0,0,0,0,0,0,0};

        for (int kk = 0; kk < 3; kk++) {
            int nb = shift_site(s, mu, kk - 1);
            const uint4* Wb = (const uint4*)(W + (long)nb * WSTRIDE);
#if CONV_DOT2
            const uint2* omp = &som[((mu * 3 + kk) * NIN) * 8 + i];
            u32 oa[NIN], ob[NIN];
#pragma unroll
            for (int j = 0; j < NIN; j++) { uint2 v = omp[j * 8]; oa[j] = v.x; ob[j] = v.y; }
#pragma unroll
            for (int e = 0; e < 9; e++) {
                uint4 a  = Wb[e * 3 + 0];
                uint4 b  = Wb[e * 3 + 1];
                uint4 cv = Wb[e * 3 + 2];
                float sr = mr[e], si = mi[e];
                cdot(a.x,  oa[0], ob[0], sr, si);
                cdot(a.y,  oa[1], ob[1], sr, si);
                cdot(a.z,  oa[2], ob[2], sr, si);
                cdot(a.w,  oa[3], ob[3], sr, si);
                cdot(b.x,  oa[4], ob[4], sr, si);
                cdot(b.y,  oa[5], ob[5], sr, si);
                cdot(b.z,  oa[6], ob[6], sr, si);
                cdot(b.w,  oa[7], ob[7], sr, si);
                cdot(cv.x, oa[8], ob[8], sr, si);
                cdot(cv.y, oa[9], ob[9], sr, si);
                mr[e] = sr; mi[e] = si;
            }
#else
            const float2* omp = &som[((mu * 3 + kk) * NIN) * 8 + i];
            float ore[NIN], oim[NIN];
#pragma unroll
            for (int j = 0; j < NIN; j++) { float2 v = omp[j * 8]; ore[j] = v.x; oim[j] = v.y; }
#pragma unroll
            for (int e = 0; e < 9; e++) {
                uint4 a  = Wb[e * 3 + 0];
                uint4 b  = Wb[e * 3 + 1];
                uint4 cv = Wb[e * 3 + 2];
                float sr = mr[e], si = mi[e];
                u32 ws[NIN] = {a.x, a.y, a.z, a.w, b.x, b.y, b.z, b.w, cv.x, cv.y};
#pragma unroll
                for (int j = 0; j < NIN; j++) {
                    float wr = __uint_as_float(ws[j] << 16);
                    float wi = __uint_as_float(ws[j] & 0xffff0000u);
                    sr = fmaf(ore[j], wr, sr); sr = fmaf(-oim[j], wi, sr);
                    si = fmaf(ore[j], wi, si); si = fmaf(oim[j], wr, si);
                }
                mr[e] = sr; mi[e] = si;
            }
#endif
        }

        // epilogue: out += A * Msum * A^H  (f32)
        M3 A;
        loadM2(A, U2, (long)s * 4 + mu);
        M3 Tm;
#pragma unroll
        for (int r = 0; r < 3; r++) {
#pragma unroll
            for (int c = 0; c < 3; c++) {
                float xr = 0.f, xi = 0.f;
#pragma unroll
                for (int k = 0; k < 3; k++) {
                    float ar = A.re[r*3+k], ai = A.im[r*3+k];
                    float br = mr[k*3+c],  bi = mi[k*3+c];
                    xr = fmaf(ar, br, xr); xr = fmaf(-ai, bi, xr);
                    xi = fmaf(ar, bi, xi); xi = fmaf(ai, br, xi);
                }
                Tm.re[r*3+c] = xr; Tm.im[r*3+c] = xi;
            }
        }
#pragma unroll
        for (int r = 0; r < 3; r++) {
#pragma unroll
            for (int c = 0; c < 3; c++) {
                float xr = 0.f, xi = 0.f;
#pragma unroll
                for (int k = 0; k < 3; k++) {
                    float ar = Tm.re[r*3+k], ai = Tm.im[r*3+k];
                    float br = A.re[c*3+k], bi = A.im[c*3+k];
                    xr = fmaf(ar, br, xr); xr = fmaf(ai, bi, xr);
                    if (MODE != 2) { xi = fmaf(ai, br, xi); xi = fmaf(-ar, bi, xi); }
                }
                accr[r*3+c] += xr;
                if (MODE != 2) acci[r*3+c] += xi;
            }
        }
    }

    long cbase = (long)tid * 9;
    if (MODE == 0) {
        float2* op = (float2*)(out + cbase * 2);
#pragma unroll
        for (int e = 0; e < 9; e++) op[e] = make_float2(accr[e], acci[e]);
    } else if (MODE == 1) {
#pragma unroll
        for (int e = 0; e < 9; e++) {
            out[cbase + e]         = accr[e];
            out[NCPLX + cbase + e] = acci[e];
        }
    } else {
#pragma unroll
        for (int e = 0; e < 9; e++) out[cbase + e] = accr[e];
    }
}

extern "C" void kernel_launch(void* const* d_in, const int* in_sizes, int n_in,
                              void* d_out, int out_size, void* d_ws, size_t ws_size,
                              hipStream_t stream) {
    const float* Ure  = (const float*)d_in[0];
    const float* Uim  = (const float*)d_in[1];
    const float* omre = (const float*)d_in[2];
    const float* omim = (const float*)d_in[3];
    float* out = (float*)d_out;

    const size_t wBytes  = (size_t)NSITE * WSTRIDE * sizeof(u32);
    const size_t u2Bytes = (size_t)NLINK * 9 * sizeof(float2);
    if (ws_size < wBytes + u2Bytes) return;

    u32*    W  = (u32*)d_ws;
    float2* U2 = (float2*)((char*)d_ws + wBytes);
    u32*    T  = (u32*)d_out;   // 18.9 MB temp in d_out; overwritten by conv

    repack_kernel<<<(NLINK * 9) / 256, 256, 0, stream>>>(Ure, Uim, U2);
    poly_kernel<<<NSITE * 4 / (16 * 16), 256, 0, stream>>>(U2, T);
    plaq_merge_kernel<<<NSITE / 32, 192, 0, stream>>>(U2, T, W);

    if (out_size == (int)NCPLX)
        conv_kernel<2><<<NSITE * 8 / 256, 256, 0, stream>>>(U2, W, omre, omim, out);
    else if (out_size == (int)(2 * NCPLX))
        conv_kernel<1><<<NSITE * 8 / 256, 256, 0, stream>>>(U2, W, omre, omim, out);
    else
        conv_kernel<0><<<NSITE * 8 / 256, 256, 0, stream>>>(U2, W, omre, omim, out);
}

// Round 8
// 368.438 us; speedup vs baseline: 3.1057x; 1.0074x over previous
//
#include <hip/hip_runtime.h>

#define LSZ   16
#define NBATCH 2
#define NSITE (NBATCH*LSZ*LSZ*LSZ*LSZ)   // 131072
#define NIN   10
#define NOUT  8
#define ND    4
#define NCPLX ((long)NSITE * NOUT * 9)   // 9,437,184 complex output elements
#define NLINE_PER_DIR (NSITE / LSZ)      // 8192
#define NLINK (NSITE * ND)               // 524288
#define WSTRIDE 108                      // u32 per site: 9 e-rows * 12 ch-slots (10 used)

typedef unsigned int u32;

struct M3 { float re[9]; float im[9]; };

// bf16 pack helpers: u32 = bf16(re) | bf16(im)<<16
__device__ __forceinline__ unsigned short f2bf(float x) {
    u32 u = __float_as_uint(x);
    u32 r = (u + 0x7fffu + ((u >> 16) & 1u)) >> 16;   // RNE
    return (unsigned short)r;
}
__device__ __forceinline__ u32 packbf(float re, float im) {
    return (u32)f2bf(re) | ((u32)f2bf(im) << 16);
}

#if __has_builtin(__builtin_amdgcn_fdot2_f32_bf16)
#define CONV_DOT2 1
typedef __bf16 bf16x2 __attribute__((ext_vector_type(2)));
__device__ __forceinline__ bf16x2 as_b2(u32 v) {
    union { u32 u; bf16x2 b; } x; x.u = v; return x.b;
}
// complex MAC: w = (wr,wi) bf16 pair; oa = (or,-oi); ob = (oi,or)
__device__ __forceinline__ void cdot(u32 w, u32 oa, u32 ob, float& sr, float& si) {
    sr = __builtin_amdgcn_fdot2_f32_bf16(as_b2(w), as_b2(oa), sr, false);
    si = __builtin_amdgcn_fdot2_f32_bf16(as_b2(w), as_b2(ob), si, false);
}
#else
#define CONV_DOT2 0
#endif

__device__ __forceinline__ void loadM2(M3& m, const float2* __restrict__ U2, long link) {
    const float2* p = U2 + link * 9;
#pragma unroll
    for (int e = 0; e < 9; e++) { float2 v = p[e]; m.re[e] = v.x; m.im[e] = v.y; }
}

// o = a * b
__device__ __forceinline__ void mulM(M3& o, const M3& a, const M3& b) {
#pragma unroll
    for (int r = 0; r < 3; r++) {
#pragma unroll
        for (int c = 0; c < 3; c++) {
            float xr = 0.f, xi = 0.f;
#pragma unroll
            for (int k = 0; k < 3; k++) {
                float ar = a.re[r*3+k], ai = a.im[r*3+k];
                float br = b.re[k*3+c], bi = b.im[k*3+c];
                xr = fmaf(ar, br, xr); xr = fmaf(-ai, bi, xr);
                xi = fmaf(ar, bi, xi); xi = fmaf(ai, br, xi);
            }
            o.re[r*3+c] = xr; o.im[r*3+c] = xi;
        }
    }
}

// o = a * b^H
__device__ __forceinline__ void mulAdjM(M3& o, const M3& a, const M3& b) {
#pragma unroll
    for (int r = 0; r < 3; r++) {
#pragma unroll
        for (int c = 0; c < 3; c++) {
            float xr = 0.f, xi = 0.f;
#pragma unroll
            for (int k = 0; k < 3; k++) {
                float ar = a.re[r*3+k], ai = a.im[r*3+k];
                float br = b.re[c*3+k], bi = b.im[c*3+k];
                xr = fmaf(ar, br, xr); xr = fmaf(ai, bi, xr);
                xi = fmaf(ai, br, xi); xi = fmaf(-ar, bi, xi);
            }
            o.re[r*3+c] = xr; o.im[r*3+c] = xi;
        }
    }
}

// site s = b*65536 + x*4096 + y*256 + z*16 + t ; mu: 0->x,1->y,2->z,3->t
__device__ __forceinline__ int shift_site(int s, int mu, int k) {
    int sh = 12 - 4 * mu;
    int c  = (s >> sh) & 15;
    int nc = (c + k) & 15;
    return (s & ~(15 << sh)) | (nc << sh);
}

// -------- Kernel 0: repack U (planar re/im) -> interleaved float2 --------
__global__ __launch_bounds__(256) void repack_kernel(const float* __restrict__ Ure,
                                                     const float* __restrict__ Uim,
                                                     float2* __restrict__ U2) {
    int t = blockIdx.x * blockDim.x + threadIdx.x;   // over NLINK*9
    U2[t] = make_float2(Ure[t], Uim[t]);
}

// ---------------- Kernel 1: Polyakov loops -> compact T (coalesced) ----------
__global__ __launch_bounds__(256) void poly_kernel(const float2* __restrict__ U2,
                                                   u32* __restrict__ T) {
    __shared__ float2 sm[16 * LSZ * 9];   // 18.4 KB

    int c = threadIdx.x & 15;
    int l = threadIdx.x >> 4;
    int line_global = blockIdx.x * 16 + l;
    int mu   = line_global / NLINE_PER_DIR;
    int lidx = line_global - mu * NLINE_PER_DIR;

    int sh   = 12 - 4 * mu;
    int low  = lidx & ((1 << sh) - 1);
    int high = lidx >> sh;
    int s_base = (high << (sh + 4)) | low;

    int sc = s_base | (c << sh);
    const float2* src = U2 + ((long)(sc * 4 + mu)) * 9;
    float2* mym = &sm[(l * LSZ + c) * 9];
#pragma unroll
    for (int e = 0; e < 9; e++) mym[e] = src[e];
    __syncthreads();

    M3 P;
    {
        const float2* m0 = &sm[(l * LSZ + c) * 9];
#pragma unroll
        for (int e = 0; e < 9; e++) { float2 v = m0[e]; P.re[e] = v.x; P.im[e] = v.y; }
    }
    for (int step = 1; step < LSZ; step++) {
        const float2* mn = &sm[(l * LSZ + ((c + step) & 15)) * 9];
        M3 Un, Tm;
#pragma unroll
        for (int e = 0; e < 9; e++) { float2 v = mn[e]; Un.re[e] = v.x; Un.im[e] = v.y; }
        mulM(Tm, P, Un);
        P = Tm;
    }

    u32* Tp = T + ((long)line_global * 9) * 16 + c;
#pragma unroll
    for (int e = 0; e < 9; e++) Tp[e * 16] = packbf(P.re[e], P.im[e]);
}

// ------- Kernel 2: plaquettes + merge-poly -> W, fully coalesced writes -------
__global__ __launch_bounds__(192) void plaq_merge_kernel(const float2* __restrict__ U2,
                                                         const u32* __restrict__ T,
                                                         u32* __restrict__ W) {
    __shared__ u32 sw[32 * WSTRIDE];   // 13824 B

    int p  = threadIdx.x >> 5;          // 0..5
    int ls = threadIdx.x & 31;          // local site
    int s0 = blockIdx.x * 32;
    int s  = s0 + ls;

    int mu = (p < 3) ? 0 : ((p < 5) ? 1 : 2);
    int nu = (mu == 0) ? (p + 1) : ((mu == 1) ? (p - 1) : 3);

    M3 Umu, Unu, Unu_f, Umu_f, T1, T2, P;
    loadM2(Umu, U2, (long)s * 4 + mu);
    loadM2(Unu, U2, (long)s * 4 + nu);
    int spmu = shift_site(s, mu, 1);
    int spnu = shift_site(s, nu, 1);
    loadM2(Unu_f, U2, (long)spmu * 4 + nu);
    loadM2(Umu_f, U2, (long)spnu * 4 + mu);

    mulM(T1, Umu, Unu_f);
    mulAdjM(T2, T1, Umu_f);
    mulAdjM(P, T2, Unu);

#pragma unroll
    for (int e = 0; e < 9; e++) sw[ls * WSTRIDE + e * 12 + p] = packbf(P.re[e], P.im[e]);

    for (int it = threadIdx.x; it < 32 * 4 * 9; it += 192) {
        int ls2 = it / 36;
        int r   = it - ls2 * 36;
        int mu2 = r / 9;
        int e2  = r - mu2 * 9;
        int s2  = s0 + ls2;
        int sh  = 12 - 4 * mu2;
        int c   = (s2 >> sh) & 15;
        int low = s2 & ((1 << sh) - 1);
        int rest = s2 >> (sh + 4);
        int lidx = (rest << sh) | low;
        long lg  = (long)mu2 * NLINE_PER_DIR + lidx;
        sw[ls2 * WSTRIDE + e2 * 12 + 6 + mu2] = T[(lg * 9 + e2) * 16 + c];
    }
    __syncthreads();

    uint4* Wv = (uint4*)(W + (long)s0 * WSTRIDE);
    const uint4* sv = (const uint4*)sw;
    for (int it = threadIdx.x; it < 32 * WSTRIDE / 4; it += 192)
        Wv[it] = sv[it];
}

// ---------------- Kernel 3: gauge-equivariant conv ----------------
// MODE 0: interleaved (re,im); MODE 1: planar [re][im]; MODE 2: real only
// Clause-structured K-loop: 9 outstanding uint4 loads per group, then 60 dot2.
template <int MODE>
__global__ __launch_bounds__(256, 4) void conv_kernel(const float2* __restrict__ U2,
                                                      const u32* __restrict__ W,
                                                      const float* __restrict__ omre,
                                                      const float* __restrict__ omim,
                                                      float* __restrict__ out) {
#if CONV_DOT2
    // som[(mk*10+j)*8 + i]: .x = bf16pair(or, -oi), .y = bf16pair(oi, or)
    __shared__ uint2 som[12 * NIN * 8];   // 7.5 KB
    for (int t = threadIdx.x; t < 12 * NIN * 8; t += blockDim.x) {
        int i  = t & 7;
        int j  = (t >> 3) % NIN;
        int mk = (t >> 3) / NIN;
        int mu = mk / 3, kk = mk % 3;
        int oidx = ((i * NIN + j) * ND + mu) * 3 + kk;
        float orv = omre[oidx], oiv = omim[oidx];
        som[t] = make_uint2(packbf(orv, -oiv), packbf(oiv, orv));
    }
#else
    __shared__ float2 som[12 * NIN * 8];   // 7.5 KB
    for (int t = threadIdx.x; t < 12 * NIN * 8; t += blockDim.x) {
        int i  = t & 7;
        int j  = (t >> 3) % NIN;
        int mk = (t >> 3) / NIN;
        int mu = mk / 3, kk = mk % 3;
        int oidx = ((i * NIN + j) * ND + mu) * 3 + kk;
        som[t] = make_float2(omre[oidx], omim[oidx]);
    }
#endif
    __shared__ float sout[256 * 9];       // 9 KB output staging (mode 2)
    __syncthreads();

    int tid = blockIdx.x * blockDim.x + threadIdx.x;
    int i = tid & 7;          // output channel
    int s = tid >> 3;         // site

    float accr[9] = {0,0,0,0,0,0,0,0,0};
    float acci[9] = {0,0,0,0,0,0,0,0,0};

    for (int mu = 0; mu < ND; mu++) {
        float mr[9] = {0,0,0,0,0,0,0,0,0};
        float mi[9] = {0,0,0,0,0,0,0,0,0};

        for (int kk = 0; kk < 3; kk++) {
            int nb = shift_site(s, mu, kk - 1);
            const uint4* Wb = (const uint4*)(W + (long)nb * WSTRIDE);
#if CONV_DOT2
            const uint2* omp = &som[((mu * 3 + kk) * NIN) * 8 + i];
            u32 oa[NIN], ob[NIN];
#pragma unroll
            for (int j = 0; j < NIN; j++) { uint2 v = omp[j * 8]; oa[j] = v.x; ob[j] = v.y; }
#pragma unroll
            for (int g = 0; g < 3; g++) {           // e-triple: 9-load clause
                uint4 w[9];
#pragma unroll
                for (int q = 0; q < 9; q++) w[q] = Wb[g * 9 + q];
#pragma unroll
                for (int ee = 0; ee < 3; ee++) {
                    int e = g * 3 + ee;
                    float sr = mr[e], si = mi[e];
                    uint4 a  = w[ee * 3 + 0];
                    uint4 b  = w[ee * 3 + 1];
                    uint4 cv = w[ee * 3 + 2];
                    cdot(a.x,  oa[0], ob[0], sr, si);
                    cdot(a.y,  oa[1], ob[1], sr, si);
                    cdot(a.z,  oa[2], ob[2], sr, si);
                    cdot(a.w,  oa[3], ob[3], sr, si);
                    cdot(b.x,  oa[4], ob[4], sr, si);
                    cdot(b.y,  oa[5], ob[5], sr, si);
                    cdot(b.z,  oa[6], ob[6], sr, si);
                    cdot(b.w,  oa[7], ob[7], sr, si);
                    cdot(cv.x, oa[8], ob[8], sr, si);
                    cdot(cv.y, oa[9], ob[9], sr, si);
                    mr[e] = sr; mi[e] = si;
                }
            }
#else
            const float2* omp = &som[((mu * 3 + kk) * NIN) * 8 + i];
            float ore[NIN], oim[NIN];
#pragma unroll
            for (int j = 0; j < NIN; j++) { float2 v = omp[j * 8]; ore[j] = v.x; oim[j] = v.y; }
#pragma unroll
            for (int g = 0; g < 3; g++) {
                uint4 w[9];
#pragma unroll
                for (int q = 0; q < 9; q++) w[q] = Wb[g * 9 + q];
#pragma unroll
                for (int ee = 0; ee < 3; ee++) {
                    int e = g * 3 + ee;
                    float sr = mr[e], si = mi[e];
                    u32 ws[NIN] = {w[ee*3+0].x, w[ee*3+0].y, w[ee*3+0].z, w[ee*3+0].w,
                                   w[ee*3+1].x, w[ee*3+1].y, w[ee*3+1].z, w[ee*3+1].w,
                                   w[ee*3+2].x, w[ee*3+2].y};
#pragma unroll
                    for (int j = 0; j < NIN; j++) {
                        float wr = __uint_as_float(ws[j] << 16);
                        float wi = __uint_as_float(ws[j] & 0xffff0000u);
                        sr = fmaf(ore[j], wr, sr); sr = fmaf(-oim[j], wi, sr);
                        si = fmaf(ore[j], wi, si); si = fmaf(oim[j], wr, si);
                    }
                    mr[e] = sr; mi[e] = si;
                }
            }
#endif
        }

        // epilogue: out += A * Msum * A^H  (f32)
        M3 A;
        loadM2(A, U2, (long)s * 4 + mu);
        M3 Tm;
#pragma unroll
        for (int r = 0; r < 3; r++) {
#pragma unroll
            for (int c = 0; c < 3; c++) {
                float xr = 0.f, xi = 0.f;
#pragma unroll
                for (int k = 0; k < 3; k++) {
                    float ar = A.re[r*3+k], ai = A.im[r*3+k];
                    float br = mr[k*3+c],  bi = mi[k*3+c];
                    xr = fmaf(ar, br, xr); xr = fmaf(-ai, bi, xr);
                    xi = fmaf(ar, bi, xi); xi = fmaf(ai, br, xi);
                }
                Tm.re[r*3+c] = xr; Tm.im[r*3+c] = xi;
            }
        }
#pragma unroll
        for (int r = 0; r < 3; r++) {
#pragma unroll
            for (int c = 0; c < 3; c++) {
                float xr = 0.f, xi = 0.f;
#pragma unroll
                for (int k = 0; k < 3; k++) {
                    float ar = Tm.re[r*3+k], ai = Tm.im[r*3+k];
                    float br = A.re[c*3+k], bi = A.im[c*3+k];
                    xr = fmaf(ar, br, xr); xr = fmaf(ai, bi, xr);
                    if (MODE != 2) { xi = fmaf(ai, br, xi); xi = fmaf(-ar, bi, xi); }
                }
                accr[r*3+c] += xr;
                if (MODE != 2) acci[r*3+c] += xi;
            }
        }
    }

    if (MODE == 2) {
        // stage through LDS -> fully coalesced linear stores
#pragma unroll
        for (int e = 0; e < 9; e++) sout[threadIdx.x * 9 + e] = accr[e];
        __syncthreads();
        long base = (long)blockIdx.x * (256 * 9);
        for (int t = threadIdx.x; t < 256 * 9; t += 256) out[base + t] = sout[t];
    } else if (MODE == 0) {
        long cbase = (long)tid * 9;
        float2* op = (float2*)(out + cbase * 2);
#pragma unroll
        for (int e = 0; e < 9; e++) op[e] = make_float2(accr[e], acci[e]);
    } else {
        long cbase = (long)tid * 9;
#pragma unroll
        for (int e = 0; e < 9; e++) {
            out[cbase + e]         = accr[e];
            out[NCPLX + cbase + e] = acci[e];
        }
    }
}

extern "C" void kernel_launch(void* const* d_in, const int* in_sizes, int n_in,
                              void* d_out, int out_size, void* d_ws, size_t ws_size,
                              hipStream_t stream) {
    const float* Ure  = (const float*)d_in[0];
    const float* Uim  = (const float*)d_in[1];
    const float* omre = (const float*)d_in[2];
    const float* omim = (const float*)d_in[3];
    float* out = (float*)d_out;

    const size_t wBytes  = (size_t)NSITE * WSTRIDE * sizeof(u32);
    const size_t u2Bytes = (size_t)NLINK * 9 * sizeof(float2);
    if (ws_size < wBytes + u2Bytes) return;

    u32*    W  = (u32*)d_ws;
    float2* U2 = (float2*)((char*)d_ws + wBytes);
    u32*    T  = (u32*)d_out;   // 18.9 MB temp in d_out; overwritten by conv

    repack_kernel<<<(NLINK * 9) / 256, 256, 0, stream>>>(Ure, Uim, U2);
    poly_kernel<<<NSITE * 4 / (16 * 16), 256, 0, stream>>>(U2, T);
    plaq_merge_kernel<<<NSITE / 32, 192, 0, stream>>>(U2, T, W);

    if (out_size == (int)NCPLX)
        conv_kernel<2><<<NSITE * 8 / 256, 256, 0, stream>>>(U2, W, omre, omim, out);
    else if (out_size == (int)(2 * NCPLX))
        conv_kernel<1><<<NSITE * 8 / 256, 256, 0, stream>>>(U2, W, omre, omim, out);
    else
        conv_kernel<0><<<NSITE * 8 / 256, 256, 0, stream>>>(U2, W, omre, omim, out);
}

// Round 9
// 367.004 us; speedup vs baseline: 3.1178x; 1.0039x over previous
//
#include <hip/hip_runtime.h>

#define LSZ   16
#define NBATCH 2
#define NSITE (NBATCH*LSZ*LSZ*LSZ*LSZ)   // 131072
#define NIN   10
#define NOUT  8
#define ND    4
#define NCPLX ((long)NSITE * NOUT * 9)   // 9,437,184 complex output elements
#define NLINE_PER_DIR (NSITE / LSZ)      // 8192
#define NLINK (NSITE * ND)               // 524288
#define WSTRIDE 108                      // u32 per site: 9 e-rows * 12 ch-slots (10 used)

typedef unsigned int u32;

struct M3 { float re[9]; float im[9]; };

// bf16 pack helpers: u32 = bf16(re) | bf16(im)<<16
__device__ __forceinline__ unsigned short f2bf(float x) {
    u32 u = __float_as_uint(x);
    u32 r = (u + 0x7fffu + ((u >> 16) & 1u)) >> 16;   // RNE
    return (unsigned short)r;
}
__device__ __forceinline__ u32 packbf(float re, float im) {
    return (u32)f2bf(re) | ((u32)f2bf(im) << 16);
}

#if __has_builtin(__builtin_amdgcn_fdot2_f32_bf16)
#define CONV_DOT2 1
typedef __bf16 bf16x2 __attribute__((ext_vector_type(2)));
__device__ __forceinline__ bf16x2 as_b2(u32 v) {
    union { u32 u; bf16x2 b; } x; x.u = v; return x.b;
}
// complex MAC: w = (wr,wi) bf16 pair; oa = (or,-oi); ob = (oi,or)
__device__ __forceinline__ void cdot(u32 w, u32 oa, u32 ob, float& sr, float& si) {
    sr = __builtin_amdgcn_fdot2_f32_bf16(as_b2(w), as_b2(oa), sr, false);
    si = __builtin_amdgcn_fdot2_f32_bf16(as_b2(w), as_b2(ob), si, false);
}
#else
#define CONV_DOT2 0
#endif

__device__ __forceinline__ void loadM2(M3& m, const float2* __restrict__ U2, long link) {
    const float2* p = U2 + link * 9;
#pragma unroll
    for (int e = 0; e < 9; e++) { float2 v = p[e]; m.re[e] = v.x; m.im[e] = v.y; }
}

// o = a * b
__device__ __forceinline__ void mulM(M3& o, const M3& a, const M3& b) {
#pragma unroll
    for (int r = 0; r < 3; r++) {
#pragma unroll
        for (int c = 0; c < 3; c++) {
            float xr = 0.f, xi = 0.f;
#pragma unroll
            for (int k = 0; k < 3; k++) {
                float ar = a.re[r*3+k], ai = a.im[r*3+k];
                float br = b.re[k*3+c], bi = b.im[k*3+c];
                xr = fmaf(ar, br, xr); xr = fmaf(-ai, bi, xr);
                xi = fmaf(ar, bi, xi); xi = fmaf(ai, br, xi);
            }
            o.re[r*3+c] = xr; o.im[r*3+c] = xi;
        }
    }
}

// o = a * b^H
__device__ __forceinline__ void mulAdjM(M3& o, const M3& a, const M3& b) {
#pragma unroll
    for (int r = 0; r < 3; r++) {
#pragma unroll
        for (int c = 0; c < 3; c++) {
            float xr = 0.f, xi = 0.f;
#pragma unroll
            for (int k = 0; k < 3; k++) {
                float ar = a.re[r*3+k], ai = a.im[r*3+k];
                float br = b.re[c*3+k], bi = b.im[c*3+k];
                xr = fmaf(ar, br, xr); xr = fmaf(ai, bi, xr);
                xi = fmaf(ai, br, xi); xi = fmaf(-ar, bi, xi);
            }
            o.re[r*3+c] = xr; o.im[r*3+c] = xi;
        }
    }
}

// site s = b*65536 + x*4096 + y*256 + z*16 + t ; mu: 0->x,1->y,2->z,3->t
__device__ __forceinline__ int shift_site(int s, int mu, int k) {
    int sh = 12 - 4 * mu;
    int c  = (s >> sh) & 15;
    int nc = (c + k) & 15;
    return (s & ~(15 << sh)) | (nc << sh);
}

// -------- Kernel 0: repack U (planar re/im) -> interleaved float2 --------
__global__ __launch_bounds__(256) void repack_kernel(const float* __restrict__ Ure,
                                                     const float* __restrict__ Uim,
                                                     float2* __restrict__ U2) {
    int t = blockIdx.x * blockDim.x + threadIdx.x;   // over NLINK*9
    U2[t] = make_float2(Ure[t], Uim[t]);
}

// ---------------- Kernel 1: Polyakov loops -> compact T (coalesced) ----------
// Staging gather ordered so consecutive elements hit consecutive sites.
// sm layout: [l (pad 145)][c*9 + e] float2; l-stride 145 -> bank stride 290%32=2.
__global__ __launch_bounds__(256) void poly_kernel(const float2* __restrict__ U2,
                                                   u32* __restrict__ T) {
    __shared__ float2 sm[16 * 145];   // 18.56 KB

    int line0 = blockIdx.x * 16;                 // 16 lines/block, same mu
    int mu    = line0 / NLINE_PER_DIR;           // block-uniform
    int lidx0 = line0 - mu * NLINE_PER_DIR;
    int sh    = 12 - 4 * mu;
    // s_base0 for lidx0 (l adds +l for mu<3 since t-bits are low)
    int low0  = lidx0 & ((1 << sh) - 1);
    int high0 = lidx0 >> sh;
    int s_base0 = (high0 << (sh + 4)) | low0;

    // cooperative staging: 256 sites x 9 float2 = 2304 elements
    for (int n = threadIdx.x; n < 16 * 16 * 9; n += 256) {
        int siteIdx = n / 9;
        int e       = n - siteIdx * 9;
        int site, l, c;
        if (mu == 3) { site = (lidx0 << 4) + siteIdx; l = siteIdx >> 4; c = siteIdx & 15; }
        else         { site = s_base0 + ((siteIdx >> 4) << sh) + (siteIdx & 15);
                       l = siteIdx & 15; c = siteIdx >> 4; }
        sm[l * 145 + c * 9 + e] = U2[((long)site * 4 + mu) * 9 + e];
    }
    __syncthreads();

    int c = threadIdx.x & 15;
    int l = threadIdx.x >> 4;

    M3 P;
    {
        const float2* m0 = &sm[l * 145 + c * 9];
#pragma unroll
        for (int e = 0; e < 9; e++) { float2 v = m0[e]; P.re[e] = v.x; P.im[e] = v.y; }
    }
    for (int step = 1; step < LSZ; step++) {
        const float2* mn = &sm[l * 145 + ((c + step) & 15) * 9];
        M3 Un, Tm;
#pragma unroll
        for (int e = 0; e < 9; e++) { float2 v = mn[e]; Un.re[e] = v.x; Un.im[e] = v.y; }
        mulM(Tm, P, Un);
        P = Tm;
    }

    int line_global = line0 + l;
    int lidx = lidx0 + l;
    int lowl  = lidx & ((1 << sh) - 1);
    int highl = lidx >> sh;
    int sc = ((highl << (sh + 4)) | lowl) | (c << sh);

    u32* Tp = T + ((long)line_global * 9) * 16 + c;
#pragma unroll
    for (int e = 0; e < 9; e++) Tp[e * 16] = packbf(P.re[e], P.im[e]);
}

// ------- Kernel 2: plaquettes + merge-poly -> W -------
// Block = 192 threads = 32 sites x 6 plaquettes. U staged via coalesced LDS:
// slots 0..2 = sites shifted +e_{x,y,z}; slot 3 = self; t+1 = rotated self.
// Per-site LDS stride padded to 37 float2 (bank stride 74%32=10 -> 2-way, free).
__global__ __launch_bounds__(192) void plaq_merge_kernel(const float2* __restrict__ U2,
                                                         const u32* __restrict__ T,
                                                         u32* __restrict__ W) {
    __shared__ float2 sU[4 * 32 * 37];   // 37,888 B
    __shared__ u32 sw[32 * WSTRIDE];     // 13,824 B   (total 51.7 KB)

    int s0 = blockIdx.x * 32;            // 2 t-lines: z in {z0,z0+1}, t 0..15

    // stage 8 runs (4 slots x 2 t-lines) x 16 sites x 36 float2
    for (int n = threadIdx.x; n < 8 * 16 * 36; n += 192) {
        int run = n / 576;               // 576 = 16*36
        int q   = n - run * 576;
        int sir = q / 36;                // site in run
        int e36 = q - sir * 36;          // link*9 + e
        int slot = run >> 1, r = run & 1;
        int base = s0 + r * 16;
        if (slot < 3) base = shift_site(base, slot, 1);
        sU[(slot * 32 + r * 16 + sir) * 37 + e36] = U2[(long)(base + sir) * 36 + e36];
    }
    __syncthreads();

    int p  = threadIdx.x >> 5;           // 0..5
    int ls = threadIdx.x & 31;           // local site
    int s  = s0 + ls;

    int mu = (p < 3) ? 0 : ((p < 5) ? 1 : 2);
    int nu = (mu == 0) ? (p + 1) : ((mu == 1) ? (p - 1) : 3);

    M3 Umu, Unu, Unu_f, Umu_f, T1, T2, P;
    {
        const float2* pp;
#define LDM(m, slot, site, link) \
        pp = &sU[((slot) * 32 + (site)) * 37 + (link) * 9]; \
        _Pragma("unroll") \
        for (int e = 0; e < 9; e++) { float2 v = pp[e]; (m).re[e] = v.x; (m).im[e] = v.y; }

        LDM(Umu, 3, ls, mu);
        LDM(Unu, 3, ls, nu);
        LDM(Unu_f, mu, ls, nu);                       // U_nu(s+e_mu), mu in {0,1,2}
        int lsrot = (ls & 16) | ((ls + 1) & 15);      // t+1 rotation inside self
        int fslot = (nu == 3) ? 3 : nu;
        int fsite = (nu == 3) ? lsrot : ls;
        LDM(Umu_f, fslot, fsite, mu);                 // U_mu(s+e_nu)
#undef LDM
    }

    mulM(T1, Umu, Unu_f);
    mulAdjM(T2, T1, Umu_f);
    mulAdjM(P, T2, Unu);

#pragma unroll
    for (int e = 0; e < 9; e++) sw[ls * WSTRIDE + e * 12 + p] = packbf(P.re[e], P.im[e]);

    // gather poly channels from T: 32 sites x 4 mu x 9 e
    for (int it = threadIdx.x; it < 32 * 4 * 9; it += 192) {
        int ls2 = it / 36;
        int r   = it - ls2 * 36;
        int mu2 = r / 9;
        int e2  = r - mu2 * 9;
        int s2  = s0 + ls2;
        int sh  = 12 - 4 * mu2;
        int c   = (s2 >> sh) & 15;
        int low = s2 & ((1 << sh) - 1);
        int rest = s2 >> (sh + 4);
        int lidx = (rest << sh) | low;
        long lg  = (long)mu2 * NLINE_PER_DIR + lidx;
        sw[ls2 * WSTRIDE + e2 * 12 + 6 + mu2] = T[(lg * 9 + e2) * 16 + c];
    }
    __syncthreads();

    uint4* Wv = (uint4*)(W + (long)s0 * WSTRIDE);
    const uint4* sv = (const uint4*)sw;
    for (int it = threadIdx.x; it < 32 * WSTRIDE / 4; it += 192)
        Wv[it] = sv[it];
}

// ---------------- Kernel 3: gauge-equivariant conv (unchanged from R8) -------
template <int MODE>
__global__ __launch_bounds__(256, 4) void conv_kernel(const float2* __restrict__ U2,
                                                      const u32* __restrict__ W,
                                                      const float* __restrict__ omre,
                                                      const float* __restrict__ omim,
                                                      float* __restrict__ out) {
#if CONV_DOT2
    __shared__ uint2 som[12 * NIN * 8];   // 7.5 KB
    for (int t = threadIdx.x; t < 12 * NIN * 8; t += blockDim.x) {
        int i  = t & 7;
        int j  = (t >> 3) % NIN;
        int mk = (t >> 3) / NIN;
        int mu = mk / 3, kk = mk % 3;
        int oidx = ((i * NIN + j) * ND + mu) * 3 + kk;
        float orv = omre[oidx], oiv = omim[oidx];
        som[t] = make_uint2(packbf(orv, -oiv), packbf(oiv, orv));
    }
#else
    __shared__ float2 som[12 * NIN * 8];
    for (int t = threadIdx.x; t < 12 * NIN * 8; t += blockDim.x) {
        int i  = t & 7;
        int j  = (t >> 3) % NIN;
        int mk = (t >> 3) / NIN;
        int mu = mk / 3, kk = mk % 3;
        int oidx = ((i * NIN + j) * ND + mu) * 3 + kk;
        som[t] = make_float2(omre[oidx], omim[oidx]);
    }
#endif
    __shared__ float sout[256 * 9];       // 9 KB output staging (mode 2)
    __syncthreads();

    int tid = blockIdx.x * blockDim.x + threadIdx.x;
    int i = tid & 7;
    int s = tid >> 3;

    float accr[9] = {0,0,0,0,0,0,0,0,0};
    float acci[9] = {0,0,0,0,0,0,0,0,0};

    for (int mu = 0; mu < ND; mu++) {
        float mr[9] = {0,0,0,0,0,0,0,0,0};
        float mi[9] = {0,0,0,0,0,0,0,0,0};

        for (int kk = 0; kk < 3; kk++) {
            int nb = shift_site(s, mu, kk - 1);
            const uint4* Wb = (const uint4*)(W + (long)nb * WSTRIDE);
#if CONV_DOT2
            const uint2* omp = &som[((mu * 3 + kk) * NIN) * 8 + i];
            u32 oa[NIN], ob[NIN];
#pragma unroll
            for (int j = 0; j < NIN; j++) { uint2 v = omp[j * 8]; oa[j] = v.x; ob[j] = v.y; }
#pragma unroll
            for (int g = 0; g < 3; g++) {
                uint4 w[9];
#pragma unroll
                for (int q = 0; q < 9; q++) w[q] = Wb[g * 9 + q];
#pragma unroll
                for (int ee = 0; ee < 3; ee++) {
                    int e = g * 3 + ee;
                    float sr = mr[e], si = mi[e];
                    uint4 a  = w[ee * 3 + 0];
                    uint4 b  = w[ee * 3 + 1];
                    uint4 cv = w[ee * 3 + 2];
                    cdot(a.x,  oa[0], ob[0], sr, si);
                    cdot(a.y,  oa[1], ob[1], sr, si);
                    cdot(a.z,  oa[2], ob[2], sr, si);
                    cdot(a.w,  oa[3], ob[3], sr, si);
                    cdot(b.x,  oa[4], ob[4], sr, si);
                    cdot(b.y,  oa[5], ob[5], sr, si);
                    cdot(b.z,  oa[6], ob[6], sr, si);
                    cdot(b.w,  oa[7], ob[7], sr, si);
                    cdot(cv.x, oa[8], ob[8], sr, si);
                    cdot(cv.y, oa[9], ob[9], sr, si);
                    mr[e] = sr; mi[e] = si;
                }
            }
#else
            const float2* omp = &som[((mu * 3 + kk) * NIN) * 8 + i];
            float ore[NIN], oim[NIN];
#pragma unroll
            for (int j = 0; j < NIN; j++) { float2 v = omp[j * 8]; ore[j] = v.x; oim[j] = v.y; }
#pragma unroll
            for (int g = 0; g < 3; g++) {
                uint4 w[9];
#pragma unroll
                for (int q = 0; q < 9; q++) w[q] = Wb[g * 9 + q];
#pragma unroll
                for (int ee = 0; ee < 3; ee++) {
                    int e = g * 3 + ee;
                    float sr = mr[e], si = mi[e];
                    u32 ws[NIN] = {w[ee*3+0].x, w[ee*3+0].y, w[ee*3+0].z, w[ee*3+0].w,
                                   w[ee*3+1].x, w[ee*3+1].y, w[ee*3+1].z, w[ee*3+1].w,
                                   w[ee*3+2].x, w[ee*3+2].y};
#pragma unroll
                    for (int j = 0; j < NIN; j++) {
                        float wr = __uint_as_float(ws[j] << 16);
                        float wi = __uint_as_float(ws[j] & 0xffff0000u);
                        sr = fmaf(ore[j], wr, sr); sr = fmaf(-oim[j], wi, sr);
                        si = fmaf(ore[j], wi, si); si = fmaf(oim[j], wr, si);
                    }
                    mr[e] = sr; mi[e] = si;
                }
            }
#endif
        }

        // epilogue: out += A * Msum * A^H  (f32)
        M3 A;
        loadM2(A, U2, (long)s * 4 + mu);
        M3 Tm;
#pragma unroll
        for (int r = 0; r < 3; r++) {
#pragma unroll
            for (int c = 0; c < 3; c++) {
                float xr = 0.f, xi = 0.f;
#pragma unroll
                for (int k = 0; k < 3; k++) {
                    float ar = A.re[r*3+k], ai = A.im[r*3+k];
                    float br = mr[k*3+c],  bi = mi[k*3+c];
                    xr = fmaf(ar, br, xr); xr = fmaf(-ai, bi, xr);
                    xi = fmaf(ar, bi, xi); xi = fmaf(ai, br, xi);
                }
                Tm.re[r*3+c] = xr; Tm.im[r*3+c] = xi;
            }
        }
#pragma unroll
        for (int r = 0; r < 3; r++) {
#pragma unroll
            for (int c = 0; c < 3; c++) {
                float xr = 0.f, xi = 0.f;
#pragma unroll
                for (int k = 0; k < 3; k++) {
                    float ar = Tm.re[r*3+k], ai = Tm.im[r*3+k];
                    float br = A.re[c*3+k], bi = A.im[c*3+k];
                    xr = fmaf(ar, br, xr); xr = fmaf(ai, bi, xr);
                    if (MODE != 2) { xi = fmaf(ai, br, xi); xi = fmaf(-ar, bi, xi); }
                }
                accr[r*3+c] += xr;
                if (MODE != 2) acci[r*3+c] += xi;
            }
        }
    }

    if (MODE == 2) {
#pragma unroll
        for (int e = 0; e < 9; e++) sout[threadIdx.x * 9 + e] = accr[e];
        __syncthreads();
        long base = (long)blockIdx.x * (256 * 9);
        for (int t = threadIdx.x; t < 256 * 9; t += 256) out[base + t] = sout[t];
    } else if (MODE == 0) {
        long cbase = (long)tid * 9;
        float2* op = (float2*)(out + cbase * 2);
#pragma unroll
        for (int e = 0; e < 9; e++) op[e] = make_float2(accr[e], acci[e]);
    } else {
        long cbase = (long)tid * 9;
#pragma unroll
        for (int e = 0; e < 9; e++) {
            out[cbase + e]         = accr[e];
            out[NCPLX + cbase + e] = acci[e];
        }
    }
}

extern "C" void kernel_launch(void* const* d_in, const int* in_sizes, int n_in,
                              void* d_out, int out_size, void* d_ws, size_t ws_size,
                              hipStream_t stream) {
    const float* Ure  = (const float*)d_in[0];
    const float* Uim  = (const float*)d_in[1];
    const float* omre = (const float*)d_in[2];
    const float* omim = (const float*)d_in[3];
    float* out = (float*)d_out;

    const size_t wBytes  = (size_t)NSITE * WSTRIDE * sizeof(u32);
    const size_t u2Bytes = (size_t)NLINK * 9 * sizeof(float2);
    if (ws_size < wBytes + u2Bytes) return;

    u32*    W  = (u32*)d_ws;
    float2* U2 = (float2*)((char*)d_ws + wBytes);
    u32*    T  = (u32*)d_out;   // 18.9 MB temp in d_out; overwritten by conv

    repack_kernel<<<(NLINK * 9) / 256, 256, 0, stream>>>(Ure, Uim, U2);
    poly_kernel<<<NSITE * 4 / (16 * 16), 256, 0, stream>>>(U2, T);
    plaq_merge_kernel<<<NSITE / 32, 192, 0, stream>>>(U2, T, W);

    if (out_size == (int)NCPLX)
        conv_kernel<2><<<NSITE * 8 / 256, 256, 0, stream>>>(U2, W, omre, omim, out);
    else if (out_size == (int)(2 * NCPLX))
        conv_kernel<1><<<NSITE * 8 / 256, 256, 0, stream>>>(U2, W, omre, omim, out);
    else
        conv_kernel<0><<<NSITE * 8 / 256, 256, 0, stream>>>(U2, W, omre, omim, out);
}

// Round 12
// 360.016 us; speedup vs baseline: 3.1783x; 1.0194x over previous
//
#include <hip/hip_runtime.h>

#define LSZ   16
#define NBATCH 2
#define NSITE (NBATCH*LSZ*LSZ*LSZ*LSZ)   // 131072
#define NIN   10
#define NOUT  8
#define ND    4
#define NCPLX ((long)NSITE * NOUT * 9)   // 9,437,184 complex output elements
#define NLINE_PER_DIR (NSITE / LSZ)      // 8192
#define NLINK (NSITE * ND)               // 524288
#define WSTRIDE 108                      // u32 per site: 9 e-rows * 12 ch-slots (10 used)

typedef unsigned int u32;

struct M3 { float re[9]; float im[9]; };

// bf16 pack helpers: u32 = bf16(lo) | bf16(hi)<<16
__device__ __forceinline__ unsigned short f2bf(float x) {
    u32 u = __float_as_uint(x);
    u32 r = (u + 0x7fffu + ((u >> 16) & 1u)) >> 16;   // RNE
    return (unsigned short)r;
}
__device__ __forceinline__ u32 packbf(float lo, float hi) {
    return (u32)f2bf(lo) | ((u32)f2bf(hi) << 16);
}

#if __has_builtin(__builtin_amdgcn_fdot2_f32_bf16)
#define CONV_DOT2 1
typedef __bf16 bf16x2 __attribute__((ext_vector_type(2)));
__device__ __forceinline__ bf16x2 as_b2(u32 v) {
    union { u32 u; bf16x2 b; } x; x.u = v; return x.b;
}
__device__ __forceinline__ void cdot(u32 w, u32 oa, u32 ob, float& sr, float& si) {
    sr = __builtin_amdgcn_fdot2_f32_bf16(as_b2(w), as_b2(oa), sr, false);
    si = __builtin_amdgcn_fdot2_f32_bf16(as_b2(w), as_b2(ob), si, false);
}
#else
#define CONV_DOT2 0
#endif

__device__ __forceinline__ void loadM2(M3& m, const float2* __restrict__ U2, long link) {
    const float2* p = U2 + link * 9;
#pragma unroll
    for (int e = 0; e < 9; e++) { float2 v = p[e]; m.re[e] = v.x; m.im[e] = v.y; }
}

// o = a * b
__device__ __forceinline__ void mulM(M3& o, const M3& a, const M3& b) {
#pragma unroll
    for (int r = 0; r < 3; r++) {
#pragma unroll
        for (int c = 0; c < 3; c++) {
            float xr = 0.f, xi = 0.f;
#pragma unroll
            for (int k = 0; k < 3; k++) {
                float ar = a.re[r*3+k], ai = a.im[r*3+k];
                float br = b.re[k*3+c], bi = b.im[k*3+c];
                xr = fmaf(ar, br, xr); xr = fmaf(-ai, bi, xr);
                xi = fmaf(ar, bi, xi); xi = fmaf(ai, br, xi);
            }
            o.re[r*3+c] = xr; o.im[r*3+c] = xi;
        }
    }
}

// o = a * b^H
__device__ __forceinline__ void mulAdjM(M3& o, const M3& a, const M3& b) {
#pragma unroll
    for (int r = 0; r < 3; r++) {
#pragma unroll
        for (int c = 0; c < 3; c++) {
            float xr = 0.f, xi = 0.f;
#pragma unroll
            for (int k = 0; k < 3; k++) {
                float ar = a.re[r*3+k], ai = a.im[r*3+k];
                float br = b.re[c*3+k], bi = b.im[c*3+k];
                xr = fmaf(ar, br, xr); xr = fmaf(ai, bi, xr);
                xi = fmaf(ai, br, xi); xi = fmaf(-ar, bi, xi);
            }
            o.re[r*3+c] = xr; o.im[r*3+c] = xi;
        }
    }
}

// site s = b*65536 + x*4096 + y*256 + z*16 + t ; mu: 0->x,1->y,2->z,3->t
__device__ __forceinline__ int shift_site(int s, int mu, int k) {
    int sh = 12 - 4 * mu;
    int c  = (s >> sh) & 15;
    int nc = (c + k) & 15;
    return (s & ~(15 << sh)) | (nc << sh);
}

// ---------------- Kernel 1: Polyakov loops -> compact T (reads planar U) -----
__global__ __launch_bounds__(256) void poly_kernel(const float* __restrict__ Ure,
                                                   const float* __restrict__ Uim,
                                                   u32* __restrict__ T) {
    __shared__ float2 sm[16 * 145];   // 18.56 KB

    int line0 = blockIdx.x * 16;
    int mu    = line0 / NLINE_PER_DIR;
    int lidx0 = line0 - mu * NLINE_PER_DIR;
    int sh    = 12 - 4 * mu;
    int low0  = lidx0 & ((1 << sh) - 1);
    int high0 = lidx0 >> sh;
    int s_base0 = (high0 << (sh + 4)) | low0;

    for (int n = threadIdx.x; n < 16 * 16 * 9; n += 256) {
        int siteIdx = n / 9;
        int e       = n - siteIdx * 9;
        int site, l, c;
        if (mu == 3) { site = (lidx0 << 4) + siteIdx; l = siteIdx >> 4; c = siteIdx & 15; }
        else         { site = s_base0 + ((siteIdx >> 4) << sh) + (siteIdx & 15);
                       l = siteIdx & 15; c = siteIdx >> 4; }
        long g = ((long)site * 4 + mu) * 9 + e;
        sm[l * 145 + c * 9 + e] = make_float2(Ure[g], Uim[g]);
    }
    __syncthreads();

    int c = threadIdx.x & 15;
    int l = threadIdx.x >> 4;

    M3 P;
    {
        const float2* m0 = &sm[l * 145 + c * 9];
#pragma unroll
        for (int e = 0; e < 9; e++) { float2 v = m0[e]; P.re[e] = v.x; P.im[e] = v.y; }
    }
    for (int step = 1; step < LSZ; step++) {
        const float2* mn = &sm[l * 145 + ((c + step) & 15) * 9];
        M3 Un, Tm;
#pragma unroll
        for (int e = 0; e < 9; e++) { float2 v = mn[e]; Un.re[e] = v.x; Un.im[e] = v.y; }
        mulM(Tm, P, Un);
        P = Tm;
    }

    int line_global = line0 + l;
    u32* Tp = T + ((long)line_global * 9) * 16 + c;
#pragma unroll
    for (int e = 0; e < 9; e++) Tp[e * 16] = packbf(P.re[e], P.im[e]);
}

// ------- Kernel 2: plaquettes + merge-poly -> W; also emits U2 (repack fused) -
__global__ __launch_bounds__(192) void plaq_merge_kernel(const float* __restrict__ Ure,
                                                         const float* __restrict__ Uim,
                                                         const u32* __restrict__ T,
                                                         u32* __restrict__ W,
                                                         float2* __restrict__ U2) {
    __shared__ float2 sU[4 * 32 * 37];   // 37,888 B
    __shared__ u32 sw[32 * WSTRIDE];     // 13,824 B

    int s0 = blockIdx.x * 32;

    for (int n = threadIdx.x; n < 8 * 16 * 36; n += 192) {
        int run = n / 576;
        int q   = n - run * 576;
        int sir = q / 36;
        int e36 = q - sir * 36;
        int slot = run >> 1, r = run & 1;
        int base = s0 + r * 16;
        if (slot < 3) base = shift_site(base, slot, 1);
        long g = (long)(base + sir) * 36 + e36;
        sU[(slot * 32 + r * 16 + sir) * 37 + e36] = make_float2(Ure[g], Uim[g]);
    }
    __syncthreads();

    // repack byproduct: write U2 for this block's 32 sites from the self slot
    for (int n = threadIdx.x; n < 32 * 36; n += 192) {
        int sir = n / 36;
        int e36 = n - sir * 36;
        U2[(long)(s0 + sir) * 36 + e36] = sU[(3 * 32 + sir) * 37 + e36];
    }

    int p  = threadIdx.x >> 5;
    int ls = threadIdx.x & 31;
    int s  = s0 + ls;

    int mu = (p < 3) ? 0 : ((p < 5) ? 1 : 2);
    int nu = (mu == 0) ? (p + 1) : ((mu == 1) ? (p - 1) : 3);

    M3 Umu, Unu, Unu_f, Umu_f, T1, T2, P;
    {
        const float2* pp;
#define LDM(m, slot, site, link) \
        pp = &sU[((slot) * 32 + (site)) * 37 + (link) * 9]; \
        _Pragma("unroll") \
        for (int e = 0; e < 9; e++) { float2 v = pp[e]; (m).re[e] = v.x; (m).im[e] = v.y; }

        LDM(Umu, 3, ls, mu);
        LDM(Unu, 3, ls, nu);
        LDM(Unu_f, mu, ls, nu);
        int lsrot = (ls & 16) | ((ls + 1) & 15);
        int fslot = (nu == 3) ? 3 : nu;
        int fsite = (nu == 3) ? lsrot : ls;
        LDM(Umu_f, fslot, fsite, mu);
#undef LDM
    }

    mulM(T1, Umu, Unu_f);
    mulAdjM(T2, T1, Umu_f);
    mulAdjM(P, T2, Unu);

#pragma unroll
    for (int e = 0; e < 9; e++) sw[ls * WSTRIDE + e * 12 + p] = packbf(P.re[e], P.im[e]);

    // pad j-slots 10,11 zeroed (keeps W blocks fully-defined for vector loads)
    for (int it = threadIdx.x; it < 32 * 9 * 2; it += 192) {
        int site = it / 18;
        int r    = it - site * 18;
        sw[site * WSTRIDE + (r >> 1) * 12 + 10 + (r & 1)] = 0u;
    }

    for (int it = threadIdx.x; it < 32 * 4 * 9; it += 192) {
        int ls2 = it / 36;
        int r   = it - ls2 * 36;
        int mu2 = r / 9;
        int e2  = r - mu2 * 9;
        int s2  = s0 + ls2;
        int sh  = 12 - 4 * mu2;
        int c   = (s2 >> sh) & 15;
        int low = s2 & ((1 << sh) - 1);
        int rest = s2 >> (sh + 4);
        int lidx = (rest << sh) | low;
        long lg  = (long)mu2 * NLINE_PER_DIR + lidx;
        sw[ls2 * WSTRIDE + e2 * 12 + 6 + mu2] = T[(lg * 9 + e2) * 16 + c];
    }
    __syncthreads();

    uint4* Wv = (uint4*)(W + (long)s0 * WSTRIDE);
    const uint4* sv = (const uint4*)sw;
    for (int it = threadIdx.x; it < 32 * WSTRIDE / 4; it += 192)
        Wv[it] = sv[it];
}

// ---------------- Kernel 3: gauge-equivariant conv (R8 scalar+dot2) ----------
// XCD-aware block swizzle: contiguous site slabs per XCD for W L2 locality.
template <int MODE>
__global__ __launch_bounds__(256, 4) void conv_kernel(const float2* __restrict__ U2,
                                                      const u32* __restrict__ W,
                                                      const float* __restrict__ omre,
                                                      const float* __restrict__ omim,
                                                      float* __restrict__ out) {
#if CONV_DOT2
    __shared__ uint2 som[12 * NIN * 8];   // 7.5 KB
    for (int t = threadIdx.x; t < 12 * NIN * 8; t += blockDim.x) {
        int i  = t & 7;
        int j  = (t >> 3) % NIN;
        int mk = (t >> 3) / NIN;
        int mu = mk / 3, kk = mk % 3;
        int oidx = ((i * NIN + j) * ND + mu) * 3 + kk;
        float orv = omre[oidx], oiv = omim[oidx];
        som[t] = make_uint2(packbf(orv, -oiv), packbf(oiv, orv));
    }
#else
    __shared__ float2 som[12 * NIN * 8];
    for (int t = threadIdx.x; t < 12 * NIN * 8; t += blockDim.x) {
        int i  = t & 7;
        int j  = (t >> 3) % NIN;
        int mk = (t >> 3) / NIN;
        int mu = mk / 3, kk = mk % 3;
        int oidx = ((i * NIN + j) * ND + mu) * 3 + kk;
        som[t] = make_float2(omre[oidx], omim[oidx]);
    }
#endif
    __shared__ float sout[256 * 9];       // 9 KB output staging (mode 2)
    __syncthreads();

    // swizzle: blocks with equal (bid & 7) share an XCD (round-robin dispatch)
    // and get a contiguous 512-block site slab -> neighbor W reads hit local L2.
    int nper  = gridDim.x >> 3;
    int bidSw = (blockIdx.x & 7) * nper + (blockIdx.x >> 3);
    int tid = bidSw * blockDim.x + threadIdx.x;
    int i = tid & 7;          // output channel
    int s = tid >> 3;         // site

    float accr[9] = {0,0,0,0,0,0,0,0,0};
    float acci[9] = {0,0,0,0,0,0,0,0,0};

    for (int mu = 0; mu < ND; mu++) {
        float mr[9] = {0,0,0,0,0,0,0,0,0};
        float mi[9] = {0,0,0,0,0,0,0,0,0};

        for (int kk = 0; kk < 3; kk++) {
            int nb = shift_site(s, mu, kk - 1);
            const uint4* Wb = (const uint4*)(W + (long)nb * WSTRIDE);
#if CONV_DOT2
            const uint2* omp = &som[((mu * 3 + kk) * NIN) * 8 + i];
            u32 oa[NIN], ob[NIN];
#pragma unroll
            for (int j = 0; j < NIN; j++) { uint2 v = omp[j * 8]; oa[j] = v.x; ob[j] = v.y; }
#pragma unroll
            for (int g = 0; g < 3; g++) {           // e-triple: 9-load clause
                uint4 w[9];
#pragma unroll
                for (int q = 0; q < 9; q++) w[q] = Wb[g * 9 + q];
#pragma unroll
                for (int ee = 0; ee < 3; ee++) {
                    int e = g * 3 + ee;
                    float sr = mr[e], si = mi[e];
                    uint4 a  = w[ee * 3 + 0];
                    uint4 b  = w[ee * 3 + 1];
                    uint4 cv = w[ee * 3 + 2];
                    cdot(a.x,  oa[0], ob[0], sr, si);
                    cdot(a.y,  oa[1], ob[1], sr, si);
                    cdot(a.z,  oa[2], ob[2], sr, si);
                    cdot(a.w,  oa[3], ob[3], sr, si);
                    cdot(b.x,  oa[4], ob[4], sr, si);
                    cdot(b.y,  oa[5], ob[5], sr, si);
                    cdot(b.z,  oa[6], ob[6], sr, si);
                    cdot(b.w,  oa[7], ob[7], sr, si);
                    cdot(cv.x, oa[8], ob[8], sr, si);
                    cdot(cv.y, oa[9], ob[9], sr, si);
                    mr[e] = sr; mi[e] = si;
                }
            }
#else
            const float2* omp = &som[((mu * 3 + kk) * NIN) * 8 + i];
            float ore[NIN], oim[NIN];
#pragma unroll
            for (int j = 0; j < NIN; j++) { float2 v = omp[j * 8]; ore[j] = v.x; oim[j] = v.y; }
#pragma unroll
            for (int g = 0; g < 3; g++) {
                uint4 w[9];
#pragma unroll
                for (int q = 0; q < 9; q++) w[q] = Wb[g * 9 + q];
#pragma unroll
                for (int ee = 0; ee < 3; ee++) {
                    int e = g * 3 + ee;
                    float sr = mr[e], si = mi[e];
                    u32 ws[NIN] = {w[ee*3+0].x, w[ee*3+0].y, w[ee*3+0].z, w[ee*3+0].w,
                                   w[ee*3+1].x, w[ee*3+1].y, w[ee*3+1].z, w[ee*3+1].w,
                                   w[ee*3+2].x, w[ee*3+2].y};
#pragma unroll
                    for (int j = 0; j < NIN; j++) {
                        float wr = __uint_as_float(ws[j] << 16);
                        float wi = __uint_as_float(ws[j] & 0xffff0000u);
                        sr = fmaf(ore[j], wr, sr); sr = fmaf(-oim[j], wi, sr);
                        si = fmaf(ore[j], wi, si); si = fmaf(oim[j], wr, si);
                    }
                    mr[e] = sr; mi[e] = si;
                }
            }
#endif
        }

        // epilogue: out += A * Msum * A^H  (f32)
        M3 A;
        loadM2(A, U2, (long)s * 4 + mu);
        M3 Tm;
#pragma unroll
        for (int r = 0; r < 3; r++) {
#pragma unroll
            for (int c = 0; c < 3; c++) {
                float xr = 0.f, xi = 0.f;
#pragma unroll
                for (int k = 0; k < 3; k++) {
                    float ar = A.re[r*3+k], ai = A.im[r*3+k];
                    float br = mr[k*3+c],  bi = mi[k*3+c];
                    xr = fmaf(ar, br, xr); xr = fmaf(-ai, bi, xr);
                    xi = fmaf(ar, bi, xi); xi = fmaf(ai, br, xi);
                }
                Tm.re[r*3+c] = xr; Tm.im[r*3+c] = xi;
            }
        }
#pragma unroll
        for (int r = 0; r < 3; r++) {
#pragma unroll
            for (int c = 0; c < 3; c++) {
                float xr = 0.f, xi = 0.f;
#pragma unroll
                for (int k = 0; k < 3; k++) {
                    float ar = Tm.re[r*3+k], ai = Tm.im[r*3+k];
                    float br = A.re[c*3+k], bi = A.im[c*3+k];
                    xr = fmaf(ar, br, xr); xr = fmaf(ai, bi, xr);
                    if (MODE != 2) { xi = fmaf(ai, br, xi); xi = fmaf(-ar, bi, xi); }
                }
                accr[r*3+c] += xr;
                if (MODE != 2) acci[r*3+c] += xi;
            }
        }
    }

    if (MODE == 2) {
        // stage through LDS -> fully coalesced linear stores
#pragma unroll
        for (int e = 0; e < 9; e++) sout[threadIdx.x * 9 + e] = accr[e];
        __syncthreads();
        long base = (long)bidSw * (256 * 9);
        for (int t = threadIdx.x; t < 256 * 9; t += 256) out[base + t] = sout[t];
    } else if (MODE == 0) {
        long cbase = (long)tid * 9;
        float2* op = (float2*)(out + cbase * 2);
#pragma unroll
        for (int e = 0; e < 9; e++) op[e] = make_float2(accr[e], acci[e]);
    } else {
        long cbase = (long)tid * 9;
#pragma unroll
        for (int e = 0; e < 9; e++) {
            out[cbase + e]         = accr[e];
            out[NCPLX + cbase + e] = acci[e];
        }
    }
}

extern "C" void kernel_launch(void* const* d_in, const int* in_sizes, int n_in,
                              void* d_out, int out_size, void* d_ws, size_t ws_size,
                              hipStream_t stream) {
    const float* Ure  = (const float*)d_in[0];
    const float* Uim  = (const float*)d_in[1];
    const float* omre = (const float*)d_in[2];
    const float* omim = (const float*)d_in[3];
    float* out = (float*)d_out;

    const size_t wBytes  = (size_t)NSITE * WSTRIDE * sizeof(u32);   // 56.6 MB
    const size_t u2Bytes = (size_t)NLINK * 9 * sizeof(float2);      // 37.7 MB
    if (ws_size < wBytes + u2Bytes) return;

    u32*    W  = (u32*)d_ws;
    float2* U2 = (float2*)((char*)d_ws + wBytes);
    u32*    T  = (u32*)d_out;   // 18.9 MB temp in d_out; overwritten by conv

    poly_kernel<<<NSITE * 4 / (16 * 16), 256, 0, stream>>>(Ure, Uim, T);
    plaq_merge_kernel<<<NSITE / 32, 192, 0, stream>>>(Ure, Uim, T, W, U2);

    if (out_size == (int)NCPLX)
        conv_kernel<2><<<NSITE * 8 / 256, 256, 0, stream>>>(U2, W, omre, omim, out);
    else if (out_size == (int)(2 * NCPLX))
        conv_kernel<1><<<NSITE * 8 / 256, 256, 0, stream>>>(U2, W, omre, omim, out);
    else
        conv_kernel<0><<<NSITE * 8 / 256, 256, 0, stream>>>(U2, W, omre, omim, out);
}

// Round 13
// 336.065 us; speedup vs baseline: 3.4048x; 1.0713x over previous
//
#include <hip/hip_runtime.h>

#define LSZ   16
#define NBATCH 2
#define NSITE (NBATCH*LSZ*LSZ*LSZ*LSZ)   // 131072
#define NIN   10
#define NOUT  8
#define ND    4
#define NCPLX ((long)NSITE * NOUT * 9)   // 9,437,184 complex output elements
#define NLINE_PER_DIR (NSITE / LSZ)      // 8192
#define NLINK (NSITE * ND)               // 524288
#define WSTRIDE 108                      // u32 per site in LDS image: 9 e * 12 ch (10 used)

typedef unsigned int u32;

struct M3 { float re[9]; float im[9]; };

// bf16 pack helpers: u32 = bf16(lo) | bf16(hi)<<16
__device__ __forceinline__ unsigned short f2bf(float x) {
    u32 u = __float_as_uint(x);
    u32 r = (u + 0x7fffu + ((u >> 16) & 1u)) >> 16;   // RNE
    return (unsigned short)r;
}
__device__ __forceinline__ u32 packbf(float lo, float hi) {
    return (u32)f2bf(lo) | ((u32)f2bf(hi) << 16);
}

#if __has_builtin(__builtin_amdgcn_fdot2_f32_bf16)
#define CONV_DOT2 1
typedef __bf16 bf16x2 __attribute__((ext_vector_type(2)));
__device__ __forceinline__ bf16x2 as_b2(u32 v) {
    union { u32 u; bf16x2 b; } x; x.u = v; return x.b;
}
__device__ __forceinline__ void cdot(u32 w, u32 oa, u32 ob, float& sr, float& si) {
    sr = __builtin_amdgcn_fdot2_f32_bf16(as_b2(w), as_b2(oa), sr, false);
    si = __builtin_amdgcn_fdot2_f32_bf16(as_b2(w), as_b2(ob), si, false);
}
#else
#define CONV_DOT2 0
// scalar fallback used inside conv loop below
#endif

__device__ __forceinline__ void loadM2(M3& m, const float2* __restrict__ U2, long link) {
    const float2* p = U2 + link * 9;
#pragma unroll
    for (int e = 0; e < 9; e++) { float2 v = p[e]; m.re[e] = v.x; m.im[e] = v.y; }
}

// o = a * b
__device__ __forceinline__ void mulM(M3& o, const M3& a, const M3& b) {
#pragma unroll
    for (int r = 0; r < 3; r++) {
#pragma unroll
        for (int c = 0; c < 3; c++) {
            float xr = 0.f, xi = 0.f;
#pragma unroll
            for (int k = 0; k < 3; k++) {
                float ar = a.re[r*3+k], ai = a.im[r*3+k];
                float br = b.re[k*3+c], bi = b.im[k*3+c];
                xr = fmaf(ar, br, xr); xr = fmaf(-ai, bi, xr);
                xi = fmaf(ar, bi, xi); xi = fmaf(ai, br, xi);
            }
            o.re[r*3+c] = xr; o.im[r*3+c] = xi;
        }
    }
}

// o = a * b^H
__device__ __forceinline__ void mulAdjM(M3& o, const M3& a, const M3& b) {
#pragma unroll
    for (int r = 0; r < 3; r++) {
#pragma unroll
        for (int c = 0; c < 3; c++) {
            float xr = 0.f, xi = 0.f;
#pragma unroll
            for (int k = 0; k < 3; k++) {
                float ar = a.re[r*3+k], ai = a.im[r*3+k];
                float br = b.re[c*3+k], bi = b.im[c*3+k];
                xr = fmaf(ar, br, xr); xr = fmaf(ai, bi, xr);
                xi = fmaf(ai, br, xi); xi = fmaf(-ar, bi, xi);
            }
            o.re[r*3+c] = xr; o.im[r*3+c] = xi;
        }
    }
}

// site s = b*65536 + x*4096 + y*256 + z*16 + t ; mu: 0->x,1->y,2->z,3->t
__device__ __forceinline__ int shift_site(int s, int mu, int k) {
    int sh = 12 - 4 * mu;
    int c  = (s >> sh) & 15;
    int nc = (c + k) & 15;
    return (s & ~(15 << sh)) | (nc << sh);
}

// ---------------- Kernel 1: Polyakov loops -> compact T (reads planar U) -----
__global__ __launch_bounds__(256) void poly_kernel(const float* __restrict__ Ure,
                                                   const float* __restrict__ Uim,
                                                   u32* __restrict__ T) {
    __shared__ float2 sm[16 * 145];   // 18.56 KB

    int line0 = blockIdx.x * 16;
    int mu    = line0 / NLINE_PER_DIR;
    int lidx0 = line0 - mu * NLINE_PER_DIR;
    int sh    = 12 - 4 * mu;
    int low0  = lidx0 & ((1 << sh) - 1);
    int high0 = lidx0 >> sh;
    int s_base0 = (high0 << (sh + 4)) | low0;

    for (int n = threadIdx.x; n < 16 * 16 * 9; n += 256) {
        int siteIdx = n / 9;
        int e       = n - siteIdx * 9;
        int site, l, c;
        if (mu == 3) { site = (lidx0 << 4) + siteIdx; l = siteIdx >> 4; c = siteIdx & 15; }
        else         { site = s_base0 + ((siteIdx >> 4) << sh) + (siteIdx & 15);
                       l = siteIdx & 15; c = siteIdx >> 4; }
        long g = ((long)site * 4 + mu) * 9 + e;
        sm[l * 145 + c * 9 + e] = make_float2(Ure[g], Uim[g]);
    }
    __syncthreads();

    int c = threadIdx.x & 15;
    int l = threadIdx.x >> 4;

    M3 P;
    {
        const float2* m0 = &sm[l * 145 + c * 9];
#pragma unroll
        for (int e = 0; e < 9; e++) { float2 v = m0[e]; P.re[e] = v.x; P.im[e] = v.y; }
    }
    for (int step = 1; step < LSZ; step++) {
        const float2* mn = &sm[l * 145 + ((c + step) & 15) * 9];
        M3 Un, Tm;
#pragma unroll
        for (int e = 0; e < 9; e++) { float2 v = mn[e]; Un.re[e] = v.x; Un.im[e] = v.y; }
        mulM(Tm, P, Un);
        P = Tm;
    }

    int line_global = line0 + l;
    u32* Tp = T + ((long)line_global * 9) * 16 + c;
#pragma unroll
    for (int e = 0; e < 9; e++) Tp[e * 16] = packbf(P.re[e], P.im[e]);
}

// ------- Kernel 2: plaquettes + merge-poly -> W planes; also emits U2 --------
// W layout: 27 planes of NSITE uint4. Plane p=(e*3+q); uint4 = j-slots 4q..4q+3
// (j=10,11 zero). Block writes 32 consecutive uint4 per plane -> coalesced.
__global__ __launch_bounds__(192) void plaq_merge_kernel(const float* __restrict__ Ure,
                                                         const float* __restrict__ Uim,
                                                         const u32* __restrict__ T,
                                                         u32* __restrict__ W,
                                                         float2* __restrict__ U2) {
    __shared__ float2 sU[4 * 32 * 37];   // 37,888 B
    __shared__ u32 sw[32 * WSTRIDE];     // 13,824 B

    int s0 = blockIdx.x * 32;

    for (int n = threadIdx.x; n < 8 * 16 * 36; n += 192) {
        int run = n / 576;
        int q   = n - run * 576;
        int sir = q / 36;
        int e36 = q - sir * 36;
        int slot = run >> 1, r = run & 1;
        int base = s0 + r * 16;
        if (slot < 3) base = shift_site(base, slot, 1);
        long g = (long)(base + sir) * 36 + e36;
        sU[(slot * 32 + r * 16 + sir) * 37 + e36] = make_float2(Ure[g], Uim[g]);
    }
    __syncthreads();

    // repack byproduct: write U2 for this block's 32 sites from the self slot
    for (int n = threadIdx.x; n < 32 * 36; n += 192) {
        int sir = n / 36;
        int e36 = n - sir * 36;
        U2[(long)(s0 + sir) * 36 + e36] = sU[(3 * 32 + sir) * 37 + e36];
    }

    int p  = threadIdx.x >> 5;
    int ls = threadIdx.x & 31;
    int s  = s0 + ls;

    int mu = (p < 3) ? 0 : ((p < 5) ? 1 : 2);
    int nu = (mu == 0) ? (p + 1) : ((mu == 1) ? (p - 1) : 3);

    M3 Umu, Unu, Unu_f, Umu_f, T1, T2, P;
    {
        const float2* pp;
#define LDM(m, slot, site, link) \
        pp = &sU[((slot) * 32 + (site)) * 37 + (link) * 9]; \
        _Pragma("unroll") \
        for (int e = 0; e < 9; e++) { float2 v = pp[e]; (m).re[e] = v.x; (m).im[e] = v.y; }

        LDM(Umu, 3, ls, mu);
        LDM(Unu, 3, ls, nu);
        LDM(Unu_f, mu, ls, nu);
        int lsrot = (ls & 16) | ((ls + 1) & 15);
        int fslot = (nu == 3) ? 3 : nu;
        int fsite = (nu == 3) ? lsrot : ls;
        LDM(Umu_f, fslot, fsite, mu);
#undef LDM
    }

    mulM(T1, Umu, Unu_f);
    mulAdjM(T2, T1, Umu_f);
    mulAdjM(P, T2, Unu);

#pragma unroll
    for (int e = 0; e < 9; e++) sw[ls * WSTRIDE + e * 12 + p] = packbf(P.re[e], P.im[e]);

    // pad j-slots 10,11 zeroed
    for (int it = threadIdx.x; it < 32 * 9 * 2; it += 192) {
        int site = it / 18;
        int r    = it - site * 18;
        sw[site * WSTRIDE + (r >> 1) * 12 + 10 + (r & 1)] = 0u;
    }

    for (int it = threadIdx.x; it < 32 * 4 * 9; it += 192) {
        int ls2 = it / 36;
        int r   = it - ls2 * 36;
        int mu2 = r / 9;
        int e2  = r - mu2 * 9;
        int s2  = s0 + ls2;
        int sh  = 12 - 4 * mu2;
        int c   = (s2 >> sh) & 15;
        int low = s2 & ((1 << sh) - 1);
        int rest = s2 >> (sh + 4);
        int lidx = (rest << sh) | low;
        long lg  = (long)mu2 * NLINE_PER_DIR + lidx;
        sw[ls2 * WSTRIDE + e2 * 12 + 6 + mu2] = T[(lg * 9 + e2) * 16 + c];
    }
    __syncthreads();

    // plane-transposed write: 27 planes x 32 consecutive uint4
    uint4* W4 = (uint4*)W;
    for (int it = threadIdx.x; it < 27 * 32; it += 192) {
        int pl  = it >> 5;
        int ls2 = it & 31;
        int e   = pl / 3, q = pl - e * 3;
        const uint4 v = *(const uint4*)(sw + ls2 * WSTRIDE + e * 12 + q * 4);
        W4[(long)pl * NSITE + s0 + ls2] = v;
    }
}

// ---------------- Kernel 3: gauge-equivariant conv (plane-W, i-paired) -------
// Wave = 16 consecutive-t sites x 4 lane-groups; lane group i0 handles output
// channels i0 and i0+4. Per (mu,kk): 27 plane loads of 16 consecutive uint4
// (256 B, 4-way broadcast -> ~2 L1 lines/instr).
template <int MODE>
__global__ __launch_bounds__(256, 3) void conv_kernel(const float2* __restrict__ U2,
                                                      const u32* __restrict__ W,
                                                      const float* __restrict__ omre,
                                                      const float* __restrict__ omim,
                                                      float* __restrict__ out) {
    __shared__ uint2 som[12 * NIN * 8];   // 7.5 KB: (mk*10+j)*8+i -> (oa, ob)
    for (int t = threadIdx.x; t < 12 * NIN * 8; t += blockDim.x) {
        int i  = t & 7;
        int j  = (t >> 3) % NIN;
        int mk = (t >> 3) / NIN;
        int mu = mk / 3, kk = mk % 3;
        int oidx = ((i * NIN + j) * ND + mu) * 3 + kk;
        float orv = omre[oidx], oiv = omim[oidx];
        som[t] = make_uint2(packbf(orv, -oiv), packbf(oiv, orv));
    }
    __shared__ float sout[64 * 72];       // 18 KB output staging (mode 2)
    __syncthreads();

    int lane = threadIdx.x & 63;
    int wv   = threadIdx.x >> 6;
    int t    = lane & 15;                 // position in t-line
    int i0   = lane >> 4;                 // 0..3; handles i0, i0+4
    int s0b  = blockIdx.x * 64;
    int sline = s0b + wv * 16;            // wave's t-line base (16-aligned)
    int s    = sline + t;

    const uint4* W4 = (const uint4*)W;

    float accr[2][9], acci[2][9];
#pragma unroll
    for (int p2 = 0; p2 < 2; p2++)
#pragma unroll
        for (int e = 0; e < 9; e++) { accr[p2][e] = 0.f; acci[p2][e] = 0.f; }

    for (int mu = 0; mu < ND; mu++) {
        float mr[2][9], mi[2][9];
#pragma unroll
        for (int p2 = 0; p2 < 2; p2++)
#pragma unroll
            for (int e = 0; e < 9; e++) { mr[p2][e] = 0.f; mi[p2][e] = 0.f; }

        for (int kk = 0; kk < 3; kk++) {
            int nb;
            if (mu < 3) nb = shift_site(s, mu, kk - 1);
            else        nb = sline + ((t + kk - 1) & 15);

            int mk = mu * 3 + kk;
            u32 oa0[NIN], ob0[NIN], oa1[NIN], ob1[NIN];
#pragma unroll
            for (int j = 0; j < NIN; j++) {
                uint2 v0 = som[(mk * NIN + j) * 8 + i0];
                uint2 v1 = som[(mk * NIN + j) * 8 + i0 + 4];
                oa0[j] = v0.x; ob0[j] = v0.y;
                oa1[j] = v1.x; ob1[j] = v1.y;
            }

#pragma unroll
            for (int g = 0; g < 3; g++) {           // e-triple: 9 plane loads
                uint4 w[9];
#pragma unroll
                for (int q = 0; q < 9; q++) w[q] = W4[(long)(g * 9 + q) * NSITE + nb];
#pragma unroll
                for (int ee = 0; ee < 3; ee++) {
                    int e = g * 3 + ee;
                    uint4 a  = w[ee * 3 + 0];
                    uint4 b  = w[ee * 3 + 1];
                    uint4 cv = w[ee * 3 + 2];
                    float sr0 = mr[0][e], si0 = mi[0][e];
                    float sr1 = mr[1][e], si1 = mi[1][e];
#if CONV_DOT2
                    cdot(a.x,  oa0[0], ob0[0], sr0, si0); cdot(a.x,  oa1[0], ob1[0], sr1, si1);
                    cdot(a.y,  oa0[1], ob0[1], sr0, si0); cdot(a.y,  oa1[1], ob1[1], sr1, si1);
                    cdot(a.z,  oa0[2], ob0[2], sr0, si0); cdot(a.z,  oa1[2], ob1[2], sr1, si1);
                    cdot(a.w,  oa0[3], ob0[3], sr0, si0); cdot(a.w,  oa1[3], ob1[3], sr1, si1);
                    cdot(b.x,  oa0[4], ob0[4], sr0, si0); cdot(b.x,  oa1[4], ob1[4], sr1, si1);
                    cdot(b.y,  oa0[5], ob0[5], sr0, si0); cdot(b.y,  oa1[5], ob1[5], sr1, si1);
                    cdot(b.z,  oa0[6], ob0[6], sr0, si0); cdot(b.z,  oa1[6], ob1[6], sr1, si1);
                    cdot(b.w,  oa0[7], ob0[7], sr0, si0); cdot(b.w,  oa1[7], ob1[7], sr1, si1);
                    cdot(cv.x, oa0[8], ob0[8], sr0, si0); cdot(cv.x, oa1[8], ob1[8], sr1, si1);
                    cdot(cv.y, oa0[9], ob0[9], sr0, si0); cdot(cv.y, oa1[9], ob1[9], sr1, si1);
#else
                    u32 ws[NIN] = {a.x, a.y, a.z, a.w, b.x, b.y, b.z, b.w, cv.x, cv.y};
#pragma unroll
                    for (int j = 0; j < NIN; j++) {
                        float wr = __uint_as_float(ws[j] << 16);
                        float wi = __uint_as_float(ws[j] & 0xffff0000u);
                        float o0r = __uint_as_float(oa0[j] << 16), o0i = __uint_as_float(ob0[j] << 16);
                        float o1r = __uint_as_float(oa1[j] << 16), o1i = __uint_as_float(ob1[j] << 16);
                        // oa = (or, -oi) packed, ob = (oi, or) packed
                        float n0i = __uint_as_float(oa0[j] & 0xffff0000u);
                        float n1i = __uint_as_float(oa1[j] & 0xffff0000u);
                        float p0r = __uint_as_float(ob0[j] & 0xffff0000u);
                        float p1r = __uint_as_float(ob1[j] & 0xffff0000u);
                        sr0 = fmaf(o0r, wr, sr0); sr0 = fmaf(n0i, wi, sr0);
                        si0 = fmaf(o0i, wr, si0); si0 = fmaf(p0r, wi, si0);
                        sr1 = fmaf(o1r, wr, sr1); sr1 = fmaf(n1i, wi, sr1);
                        si1 = fmaf(o1i, wr, si1); si1 = fmaf(p1r, wi, si1);
                    }
#endif
                    mr[0][e] = sr0; mi[0][e] = si0;
                    mr[1][e] = sr1; mi[1][e] = si1;
                }
            }
        }

        // epilogue: out += A * Msum * A^H  (f32), for both i channels
        M3 A;
        loadM2(A, U2, (long)s * 4 + mu);
#pragma unroll
        for (int p2 = 0; p2 < 2; p2++) {
            M3 Tm;
#pragma unroll
            for (int r = 0; r < 3; r++) {
#pragma unroll
                for (int c = 0; c < 3; c++) {
                    float xr = 0.f, xi = 0.f;
#pragma unroll
                    for (int k = 0; k < 3; k++) {
                        float ar = A.re[r*3+k], ai = A.im[r*3+k];
                        float br = mr[p2][k*3+c], bi = mi[p2][k*3+c];
                        xr = fmaf(ar, br, xr); xr = fmaf(-ai, bi, xr);
                        xi = fmaf(ar, bi, xi); xi = fmaf(ai, br, xi);
                    }
                    Tm.re[r*3+c] = xr; Tm.im[r*3+c] = xi;
                }
            }
#pragma unroll
            for (int r = 0; r < 3; r++) {
#pragma unroll
                for (int c = 0; c < 3; c++) {
                    float xr = 0.f, xi = 0.f;
#pragma unroll
                    for (int k = 0; k < 3; k++) {
                        float ar = Tm.re[r*3+k], ai = Tm.im[r*3+k];
                        float br = A.re[c*3+k], bi = A.im[c*3+k];
                        xr = fmaf(ar, br, xr); xr = fmaf(ai, bi, xr);
                        if (MODE != 2) { xi = fmaf(ai, br, xi); xi = fmaf(-ar, bi, xi); }
                    }
                    accr[p2][r*3+c] += xr;
                    if (MODE != 2) acci[p2][r*3+c] += xi;
                }
            }
        }
    }

    if (MODE == 2) {
#pragma unroll
        for (int p2 = 0; p2 < 2; p2++) {
            int i = i0 + p2 * 4;
#pragma unroll
            for (int e = 0; e < 9; e++)
                sout[((wv * 16 + t) * 8 + i) * 9 + e] = accr[p2][e];
        }
        __syncthreads();
        long base = (long)blockIdx.x * 4608;
        for (int n = threadIdx.x; n < 4608; n += 256) out[base + n] = sout[n];
    } else if (MODE == 0) {
#pragma unroll
        for (int p2 = 0; p2 < 2; p2++) {
            int i = i0 + p2 * 4;
            long cb = ((long)s * 8 + i) * 9;
            float2* op = (float2*)(out + cb * 2);
#pragma unroll
            for (int e = 0; e < 9; e++) op[e] = make_float2(accr[p2][e], acci[p2][e]);
        }
    } else {
#pragma unroll
        for (int p2 = 0; p2 < 2; p2++) {
            int i = i0 + p2 * 4;
            long cb = ((long)s * 8 + i) * 9;
#pragma unroll
            for (int e = 0; e < 9; e++) {
                out[cb + e]         = accr[p2][e];
                out[NCPLX + cb + e] = acci[p2][e];
            }
        }
    }
}

extern "C" void kernel_launch(void* const* d_in, const int* in_sizes, int n_in,
                              void* d_out, int out_size, void* d_ws, size_t ws_size,
                              hipStream_t stream) {
    const float* Ure  = (const float*)d_in[0];
    const float* Uim  = (const float*)d_in[1];
    const float* omre = (const float*)d_in[2];
    const float* omim = (const float*)d_in[3];
    float* out = (float*)d_out;

    const size_t wBytes  = (size_t)NSITE * WSTRIDE * sizeof(u32);   // 56.6 MB (27 planes)
    const size_t u2Bytes = (size_t)NLINK * 9 * sizeof(float2);      // 37.7 MB
    if (ws_size < wBytes + u2Bytes) return;

    u32*    W  = (u32*)d_ws;
    float2* U2 = (float2*)((char*)d_ws + wBytes);
    u32*    T  = (u32*)d_out;   // 18.9 MB temp in d_out; overwritten by conv

    poly_kernel<<<NSITE * 4 / (16 * 16), 256, 0, stream>>>(Ure, Uim, T);
    plaq_merge_kernel<<<NSITE / 32, 192, 0, stream>>>(Ure, Uim, T, W, U2);

    const int convGrid = NSITE * 4 / 256;   // 2048 blocks, 64 sites each
    if (out_size == (int)NCPLX)
        conv_kernel<2><<<convGrid, 256, 0, stream>>>(U2, W, omre, omim, out);
    else if (out_size == (int)(2 * NCPLX))
        conv_kernel<1><<<convGrid, 256, 0, stream>>>(U2, W, omre, omim, out);
    else
        conv_kernel<0><<<convGrid, 256, 0, stream>>>(U2, W, omre, omim, out);
}